// Round 1
// baseline (87647.107 us; speedup 1.0000x reference)
//
#include <hip/hip_runtime.h>
#include <math.h>

// Problem constants
#define BATCH 32
#define HDIM 128
#define ZDIM 32
#define KSTEPS 6
// spatial: 128 -> 64 -> 32

__device__ __forceinline__ float softplusf(float x){
    return fmaxf(x, 0.f) + log1pf(expf(-fabsf(x)));
}
__device__ __forceinline__ float sigmoidf(float x){
    return 1.f / (1.f + expf(-x));
}
__device__ __forceinline__ float logsigf(float x){
    return fminf(x, 0.f) - log1pf(expf(-fabsf(x)));
}

// ---------------- stem1: conv 5x5 stride 2, 3->128, in 128x128 -> out 64x64, ReLU
__global__ __launch_bounds__(256) void stem1_k(const float* __restrict__ x,
                                               const float* __restrict__ Wt,
                                               const float* __restrict__ bias,
                                               float* __restrict__ out){
    __shared__ float w[75];
    int flat = blockIdx.x * 256 + threadIdx.x;
    int ox = flat & 63, oy = (flat >> 6) & 63, co = (flat >> 12) & 127, n = flat >> 19;
    if (threadIdx.x < 75) w[threadIdx.x] = Wt[co * 75 + threadIdx.x];
    __syncthreads();
    float acc = bias[co];
    const float* xb = x + n * 3 * 128 * 128;
    for (int ci = 0; ci < 3; ++ci){
        const float* xc = xb + (ci << 14);
        const float* wc = w + ci * 25;
        #pragma unroll
        for (int ky = 0; ky < 5; ++ky){
            int iy = oy * 2 - 1 + ky;             // SAME pad: lo=1
            if ((unsigned)iy >= 128u) continue;
            const float* xr = xc + (iy << 7);
            #pragma unroll
            for (int kx = 0; kx < 5; ++kx){
                int ix = ox * 2 - 1 + kx;
                if ((unsigned)ix >= 128u) continue;
                acc += xr[ix] * wc[ky * 5 + kx];
            }
        }
    }
    out[flat] = fmaxf(acc, 0.f);
}

// ---------------- stem2: conv 5x5 stride 2, 128->128, in 64x64 -> out 32x32, ReLU
__global__ __launch_bounds__(256) void stem2_k(const float* __restrict__ in,
                                               const float* __restrict__ Wt,
                                               const float* __restrict__ bias,
                                               float* __restrict__ out){
    __shared__ float w[HDIM * 25]; // 3200 floats
    int flat = blockIdx.x * 256 + threadIdx.x;
    int ox = flat & 31, oy = (flat >> 5) & 31, co = (flat >> 10) & 127, n = flat >> 17;
    for (int i = threadIdx.x; i < HDIM * 25; i += 256) w[i] = Wt[co * HDIM * 25 + i];
    __syncthreads();
    float acc = bias[co];
    const float* ib = in + n * HDIM * 64 * 64;
    for (int ci = 0; ci < HDIM; ++ci){
        const float* ic = ib + (ci << 12);
        const float* wc = w + ci * 25;
        #pragma unroll
        for (int ky = 0; ky < 5; ++ky){
            int iy = oy * 2 - 1 + ky;             // SAME pad: lo=1
            if ((unsigned)iy >= 64u) continue;
            const float* ir = ic + (iy << 6);
            #pragma unroll
            for (int kx = 0; kx < 5; ++kx){
                int ix = ox * 2 - 1 + kx;
                if ((unsigned)ix >= 64u) continue;
                acc += ir[ix] * wc[ky * 5 + kx];
            }
        }
    }
    out[flat] = fmaxf(acc, 0.f);
}

// ---------------- gauss head: 1x1 conv 128->64 (mu | logvar), z = mu + s*eps, KL vs N(0,1)
__global__ __launch_bounds__(256) void gauss_k(const float* __restrict__ h,
                                               const float* __restrict__ Wg,
                                               const float* __restrict__ bg,
                                               const float* __restrict__ eps0,
                                               float* __restrict__ z0,
                                               float* __restrict__ kl_out){
    __shared__ float w[64 * 128];
    int flat = blockIdx.x * 256 + threadIdx.x;   // [n][zc][pix], 32*32*1024
    int pix = flat & 1023, zc = (flat >> 10) & 31, n = flat >> 15;
    for (int i = threadIdx.x; i < 64 * 128; i += 256) w[i] = Wg[i];
    __syncthreads();
    const float* hb = h + n * HDIM * 1024 + pix;
    float amu = bg[zc], alv = bg[zc + 32];
    for (int ci = 0; ci < HDIM; ++ci){
        float hv = hb[ci << 10];
        amu += hv * w[zc * 128 + ci];
        alv += hv * w[(zc + 32) * 128 + ci];
    }
    float s = softplusf(alv + 0.5f) + 1e-8f;
    z0[flat] = amu + s * eps0[flat];
    float kl = -logf(s) + 0.5f * (s * s + amu * amu) - 0.5f;
    kl_out[flat * KSTEPS + 0] = kl;
}

// ---------------- generic 5x5 stride-1 SAME gates conv: out[n,256,32,32] = b + sum_j conv(src_j, W_j)
__global__ __launch_bounds__(256) void gates_k(const float* __restrict__ s0, int C0, const float* __restrict__ w0, int st0,
                                               const float* __restrict__ s1, int C1, const float* __restrict__ w1, int st1,
                                               const float* __restrict__ s2, int C2, const float* __restrict__ w2, int st2,
                                               const float* __restrict__ bias, float* __restrict__ out){
    extern __shared__ float wl[]; // (C0+C1+C2)*25 floats
    int co = (blockIdx.x >> 2) & 255, n = blockIdx.x >> 10;
    int pix = ((blockIdx.x & 3) << 8) + threadIdx.x;
    int oy = pix >> 5, ox = pix & 31;
    for (int i = threadIdx.x; i < C0 * 25; i += 256) wl[i] = w0[co * st0 + i];
    for (int i = threadIdx.x; i < C1 * 25; i += 256) wl[C0 * 25 + i] = w1[co * st1 + i];
    for (int i = threadIdx.x; i < C2 * 25; i += 256) wl[(C0 + C1) * 25 + i] = w2[co * st2 + i];
    __syncthreads();
    float acc = bias[co];
    const float* srcs[3] = { s0, s1, s2 };
    int Cs[3] = { C0, C1, C2 };
    int woff = 0;
    for (int j = 0; j < 3; ++j){
        int Cj = Cs[j];
        if (Cj == 0) continue;
        const float* sb = srcs[j] + n * Cj * 1024;
        for (int ci = 0; ci < Cj; ++ci){
            const float* ic = sb + (ci << 10);
            const float* wc = wl + woff + ci * 25;
            #pragma unroll
            for (int ky = 0; ky < 5; ++ky){
                int iy = oy - 2 + ky;
                if ((unsigned)iy >= 32u) continue;
                const float* ir = ic + (iy << 5);
                #pragma unroll
                for (int kx = 0; kx < 5; ++kx){
                    int ix = ox - 2 + kx;
                    if ((unsigned)ix >= 32u) continue;
                    acc += ir[ix] * wc[ky * 5 + kx];
                }
            }
        }
        woff += Cj * 25;
    }
    out[((n * 256 + co) << 10) + pix] = acc;
}

// ---------------- LSTM pointwise update (in-place on c,h)
__global__ __launch_bounds__(256) void lstm_k(const float* __restrict__ gates,
                                              float* __restrict__ c, float* __restrict__ h){
    int flat = blockIdx.x * 256 + threadIdx.x;   // [n][ch<64][pix]: 32*64*1024
    int pix = flat & 1023, ch = (flat >> 10) & 63, n = flat >> 16;
    const float* gb = gates + ((n * 256 + ch) << 10) + pix;
    float ig = gb[0];
    float fg = gb[64 << 10];
    float gg = gb[128 << 10];
    float og = gb[192 << 10];
    float cv = c[flat];
    float c2 = sigmoidf(fg) * cv + sigmoidf(ig) * tanhf(gg);
    float h2 = sigmoidf(og) * tanhf(c2);
    c[flat] = c2;
    h[flat] = h2;
}

// ---------------- postlin: 1x1 conv 64->64 on h_q; z = mu + s*eps; save mu,s
__global__ __launch_bounds__(256) void postlin_k(const float* __restrict__ hq,
                                                 const float* __restrict__ Wl,
                                                 const float* __restrict__ bl,
                                                 const float* __restrict__ eps_s,
                                                 float* __restrict__ z_out,
                                                 float* __restrict__ qmu, float* __restrict__ qs){
    __shared__ float w[64 * 64];
    int flat = blockIdx.x * 256 + threadIdx.x;   // [n][zc][pix]
    int pix = flat & 1023, zc = (flat >> 10) & 31, n = flat >> 15;
    for (int i = threadIdx.x; i < 64 * 64; i += 256) w[i] = Wl[i];
    __syncthreads();
    const float* hb = hq + ((n * 64) << 10) + pix;
    float amu = bl[zc], alv = bl[zc + 32];
    for (int ci = 0; ci < 64; ++ci){
        float hv = hb[ci << 10];
        amu += hv * w[zc * 64 + ci];
        alv += hv * w[(zc + 32) * 64 + ci];
    }
    float s = softplusf(alv + 0.5f) + 1e-8f;
    z_out[flat] = amu + s * eps_s[flat];
    qmu[flat] = amu;
    qs[flat] = s;
}

// ---------------- priorlin + KL
__global__ __launch_bounds__(256) void priorlin_k(const float* __restrict__ hp,
                                                  const float* __restrict__ Wl,
                                                  const float* __restrict__ bl,
                                                  const float* __restrict__ qmu,
                                                  const float* __restrict__ qs,
                                                  float* __restrict__ kl_out, int step){
    __shared__ float w[64 * 64];
    int flat = blockIdx.x * 256 + threadIdx.x;
    int pix = flat & 1023, zc = (flat >> 10) & 31, n = flat >> 15;
    for (int i = threadIdx.x; i < 64 * 64; i += 256) w[i] = Wl[i];
    __syncthreads();
    const float* hb = hp + ((n * 64) << 10) + pix;
    float amu = bl[zc], alv = bl[zc + 32];
    for (int ci = 0; ci < 64; ++ci){
        float hv = hb[ci << 10];
        amu += hv * w[zc * 64 + ci];
        alv += hv * w[(zc + 32) * 64 + ci];
    }
    float ps = softplusf(alv + 0.5f) + 1e-8f;
    float qm = qmu[flat], q = qs[flat];
    float d = qm - amu;
    float kl = logf(ps / q) + (q * q + d * d) / (2.f * ps * ps) - 0.5f;
    kl_out[flat * KSTEPS + step] = kl;
}

// ---------------- dec1: conv_transpose 4x4 stride 2 SAME, 32->128, 32x32 -> 64x64, ReLU
__global__ __launch_bounds__(256) void dec1_k(const float* __restrict__ z,
                                              const float* __restrict__ Wt,
                                              const float* __restrict__ bias,
                                              float* __restrict__ out){
    __shared__ float w[ZDIM * 16]; // 512
    int flat = blockIdx.x * 256 + threadIdx.x;   // [n][co][oy][ox] 32*128*64*64
    int ox = flat & 63, oy = (flat >> 6) & 63, co = (flat >> 12) & 127, n = flat >> 19;
    for (int i = threadIdx.x; i < ZDIM * 16; i += 256) w[i] = Wt[co * ZDIM * 16 + i];
    __syncthreads();
    float acc = bias[co];
    const float* zb = z + ((n * ZDIM) << 10);
    #pragma unroll
    for (int ky = 0; ky < 4; ++ky){
        int t = oy - 2 + ky;
        if (t & 1) continue;                      // lhs-dilation parity
        int iy = t >> 1;
        if ((unsigned)iy >= 32u) continue;
        #pragma unroll
        for (int kx = 0; kx < 4; ++kx){
            int tx = ox - 2 + kx;
            if (tx & 1) continue;
            int ix = tx >> 1;
            if ((unsigned)ix >= 32u) continue;
            const float* zp = zb + (iy << 5) + ix;
            const float* wp = w + ky * 4 + kx;
            for (int ci = 0; ci < ZDIM; ++ci){
                acc += zp[ci << 10] * wp[ci * 16];
            }
        }
    }
    out[flat] = fmaxf(acc, 0.f);
}

// ---------------- dec2: conv_transpose 4x4 stride 2 SAME, 128->1, 64x64 -> 128x128
__global__ __launch_bounds__(256) void dec2_k(const float* __restrict__ a,
                                              const float* __restrict__ Wt,
                                              const float* __restrict__ bias,
                                              float* __restrict__ out){
    __shared__ float w[HDIM * 16]; // 2048
    int flat = blockIdx.x * 256 + threadIdx.x;   // [n][oy][ox] 32*128*128
    int ox = flat & 127, oy = (flat >> 7) & 127, n = flat >> 14;
    for (int i = threadIdx.x; i < HDIM * 16; i += 256) w[i] = Wt[i];
    __syncthreads();
    float acc = bias[0];
    const float* ab = a + n * HDIM * 4096;
    #pragma unroll
    for (int ky = 0; ky < 4; ++ky){
        int t = oy - 2 + ky;
        if (t & 1) continue;
        int iy = t >> 1;
        if ((unsigned)iy >= 64u) continue;
        #pragma unroll
        for (int kx = 0; kx < 4; ++kx){
            int tx = ox - 2 + kx;
            if (tx & 1) continue;
            int ix = tx >> 1;
            if ((unsigned)ix >= 64u) continue;
            const float* ap = ab + (iy << 6) + ix;
            const float* wp = w + ky * 4 + kx;
            for (int ci = 0; ci < HDIM; ++ci){
                acc += ap[ci << 12] * wp[ci * 16];
            }
        }
    }
    out[flat] = acc;
}

// ---------------- stick-breaking accumulation over K decoder outputs
__global__ __launch_bounds__(256) void stick_k(const float* __restrict__ dec,
                                               float* __restrict__ lm){
    int flat = blockIdx.x * 256 + threadIdx.x;   // [n][pix] 32*16384
    float ss = 0.f;
    #pragma unroll
    for (int k = 0; k < KSTEPS; ++k){
        float v = dec[k * (BATCH * 16384) + flat];
        if (k < KSTEPS - 1){
            lm[k * (BATCH * 16384) + flat] = ss + logsigf(v);
            ss += logsigf(-v);
        } else {
            lm[k * (BATCH * 16384) + flat] = ss + logsigf(v);
        }
    }
}

extern "C" void kernel_launch(void* const* d_in, const int* in_sizes, int n_in,
                              void* d_out, int out_size, void* d_ws, size_t ws_size,
                              hipStream_t stream){
    const float* x        = (const float*)d_in[0];
    const float* eps      = (const float*)d_in[1];
    const float* stem1_W  = (const float*)d_in[2];
    const float* stem1_b  = (const float*)d_in[3];
    const float* stem2_W  = (const float*)d_in[4];
    const float* stem2_b  = (const float*)d_in[5];
    const float* gauss_W  = (const float*)d_in[6];
    const float* gauss_b  = (const float*)d_in[7];
    const float* post_Wx  = (const float*)d_in[8];
    const float* post_Wh  = (const float*)d_in[9];
    const float* post_b   = (const float*)d_in[10];
    const float* postlin_W= (const float*)d_in[11];
    const float* postlin_b= (const float*)d_in[12];
    const float* prior_Wx = (const float*)d_in[13];
    const float* prior_Wh = (const float*)d_in[14];
    const float* prior_b  = (const float*)d_in[15];
    const float* priorlin_W=(const float*)d_in[16];
    const float* priorlin_b=(const float*)d_in[17];
    const float* dec1_W   = (const float*)d_in[18];
    const float* dec1_b   = (const float*)d_in[19];
    const float* dec2_W   = (const float*)d_in[20];
    const float* dec2_b   = (const float*)d_in[21];

    float* lm_out = (float*)d_out;                         // [6,32,1,128,128]
    float* kl_out = lm_out + KSTEPS * BATCH * 16384;       // [32,32,32,32,6]

    float* p = (float*)d_ws;
    float* h1    = p; p += (size_t)BATCH * HDIM * 64 * 64;   // 16,777,216 (also dec1 tmp)
    float* h2    = p; p += (size_t)BATCH * HDIM * 32 * 32;   //  4,194,304
    float* zs    = p; p += (size_t)KSTEPS * BATCH * ZDIM * 1024; // 6,291,456
    float* cq    = p; p += (size_t)BATCH * 64 * 1024;        //  2,097,152
    float* hq    = p; p += (size_t)BATCH * 64 * 1024;
    float* cp    = p; p += (size_t)BATCH * 64 * 1024;
    float* hp    = p; p += (size_t)BATCH * 64 * 1024;
    float* gates = p; p += (size_t)BATCH * 256 * 1024;       //  8,388,608
    float* qmu   = p; p += (size_t)BATCH * ZDIM * 1024;
    float* qs    = p; p += (size_t)BATCH * ZDIM * 1024;
    float* dco   = p; p += (size_t)KSTEPS * BATCH * 16384;   //  3,145,728

    // zero LSTM states (cq,hq,cp,hp contiguous)
    hipMemsetAsync(cq, 0, (size_t)4 * BATCH * 64 * 1024 * sizeof(float), stream);

    stem1_k<<<65536, 256, 0, stream>>>(x, stem1_W, stem1_b, h1);
    stem2_k<<<16384, 256, 0, stream>>>(h1, stem2_W, stem2_b, h2);
    gauss_k<<<4096, 256, 0, stream>>>(h2, gauss_W, gauss_b, eps, zs, kl_out);

    for (int s = 0; s < KSTEPS - 1; ++s){
        const float* zprev = zs + (size_t)s * BATCH * ZDIM * 1024 / 32 * 32; // = zs + s*1048576
        zprev = zs + (size_t)s * 1048576;
        // posterior gates: conv(concat[h2, z], post_Wx) + conv(hq, post_Wh) + b
        gates_k<<<32768, 256, 224 * 25 * sizeof(float), stream>>>(
            h2, 128, post_Wx, 160 * 25,
            zprev, 32, post_Wx + 128 * 25, 160 * 25,
            hq, 64, post_Wh, 64 * 25,
            post_b, gates);
        lstm_k<<<8192, 256, 0, stream>>>(gates, cq, hq);
        postlin_k<<<4096, 256, 0, stream>>>(hq, postlin_W, postlin_b,
                                            eps + (size_t)(s + 1) * 1048576,
                                            zs + (size_t)(s + 1) * 1048576, qmu, qs);
        // prior gates: conv(z, prior_Wx) + conv(hp, prior_Wh) + b
        gates_k<<<32768, 256, 96 * 25 * sizeof(float), stream>>>(
            zprev, 32, prior_Wx, 32 * 25,
            hp, 64, prior_Wh, 64 * 25,
            (const float*)nullptr, 0, (const float*)nullptr, 0,
            prior_b, gates);
        lstm_k<<<8192, 256, 0, stream>>>(gates, cp, hp);
        priorlin_k<<<4096, 256, 0, stream>>>(hp, priorlin_W, priorlin_b, qmu, qs, kl_out, s + 1);
    }

    for (int k = 0; k < KSTEPS; ++k){
        dec1_k<<<65536, 256, 0, stream>>>(zs + (size_t)k * 1048576, dec1_W, dec1_b, h1);
        dec2_k<<<2048, 256, 0, stream>>>(h1, dec2_W, dec2_b, dco + (size_t)k * BATCH * 16384);
    }
    stick_k<<<2048, 256, 0, stream>>>(dco, lm_out);
}

// Round 2
// 12065.816 us; speedup vs baseline: 7.2641x; 7.2641x over previous
//
#include <hip/hip_runtime.h>
#include <math.h>

// Problem constants
#define BATCH 32
#define HDIM 128
#define ZDIM 32
#define KSTEPS 6
// spatial: 128 -> 64 -> 32

__device__ __forceinline__ float softplusf(float x){
    return fmaxf(x, 0.f) + log1pf(expf(-fabsf(x)));
}
__device__ __forceinline__ float sigmoidf(float x){
    return 1.f / (1.f + expf(-x));
}
__device__ __forceinline__ float logsigf(float x){
    return fminf(x, 0.f) - log1pf(expf(-fabsf(x)));
}

// ---------------- stem1: conv 5x5 stride 2, 3->128, in 128x128 -> out 64x64, ReLU
__global__ __launch_bounds__(256) void stem1_k(const float* __restrict__ x,
                                               const float* __restrict__ Wt,
                                               const float* __restrict__ bias,
                                               float* __restrict__ out){
    __shared__ float w[75];
    int flat = blockIdx.x * 256 + threadIdx.x;
    int ox = flat & 63, oy = (flat >> 6) & 63, co = (flat >> 12) & 127, n = flat >> 19;
    if (threadIdx.x < 75) w[threadIdx.x] = Wt[co * 75 + threadIdx.x];
    __syncthreads();
    float acc = bias[co];
    const float* xb = x + n * 3 * 128 * 128;
    for (int ci = 0; ci < 3; ++ci){
        const float* xc = xb + (ci << 14);
        const float* wc = w + ci * 25;
        #pragma unroll
        for (int ky = 0; ky < 5; ++ky){
            int iy = oy * 2 - 1 + ky;             // SAME pad: lo=1
            if ((unsigned)iy >= 128u) continue;
            const float* xr = xc + (iy << 7);
            #pragma unroll
            for (int kx = 0; kx < 5; ++kx){
                int ix = ox * 2 - 1 + kx;
                if ((unsigned)ix >= 128u) continue;
                acc += xr[ix] * wc[ky * 5 + kx];
            }
        }
    }
    out[flat] = fmaxf(acc, 0.f);
}

// ---------------- stem2 tiled: conv 5x5 stride 2 SAME, 128->128, 64x64 -> 32x32, ReLU
// block: 256 thr = 4 cg x 64 pg ; thread: 8co x 8px ; block covers 32 co x (32x16) out tile
// grid: (4 co-blocks, 2 y-halves, 32 n)
#define S2_IW 76   // padded LDS row width (cols: ix+4, ix in [-4..71])
__global__ __launch_bounds__(256) void conv5s2_k(const float* __restrict__ in,
                                                 const float* __restrict__ Wt,
                                                 const float* __restrict__ bias,
                                                 float* __restrict__ out){
    __shared__ float in_s[4 * 35 * S2_IW];   // 4ci x 35 rows x 76
    __shared__ float w_s[4 * 25 * 32];       // [ci][tap][co32]
    const int cob = blockIdx.x * 32;         // 32 co per block
    const int yh  = blockIdx.y;              // 0/1 : out rows [16*yh .. 16*yh+15]
    const int n   = blockIdx.z;
    const int tid = threadIdx.x;
    const int cg  = tid >> 6;                // 0..3  -> co sub-base cg*8
    const int pg  = tid & 63;
    const int oyl = pg >> 2;                 // 0..15
    const int xg  = pg & 3;                  // 8 px each
    const int oy  = yh * 16 + oyl;

    float acc[8][8];
    #pragma unroll
    for (int c = 0; c < 8; ++c){
        float b = bias[cob + cg * 8 + c];
        #pragma unroll
        for (int p = 0; p < 8; ++p) acc[c][p] = b;
    }

    const float* ib = in + (size_t)n * HDIM * 4096;
    for (int cb = 0; cb < HDIM; cb += 4){
        __syncthreads();
        // stage input: rows yy in [0..34] <-> iy = 32*yh - 1 + yy ; cols xx <-> ix = xx-4
        for (int idx = tid; idx < 4 * 35 * S2_IW; idx += 256){
            int ci = idx / (35 * S2_IW); int r = idx - ci * (35 * S2_IW);
            int yy = r / S2_IW, xx = r - yy * S2_IW;
            int iy = 32 * yh - 1 + yy, ix = xx - 4;
            float v = 0.f;
            if ((unsigned)iy < 64u && (unsigned)ix < 64u)
                v = ib[((cb + ci) << 12) + (iy << 6) + ix];
            in_s[idx] = v;
        }
        // stage weights transposed: [ci][tap][co32]
        for (int idx = tid; idx < 4 * 25 * 32; idx += 256){
            int ci = idx / 800; int r = idx - ci * 800;
            int tap = r >> 5; int col = r & 31;
            w_s[idx] = Wt[(cob + col) * (HDIM * 25) + (cb + ci) * 25 + tap];
        }
        __syncthreads();
        #pragma unroll
        for (int ci = 0; ci < 4; ++ci){
            #pragma unroll
            for (int ky = 0; ky < 5; ++ky){
                int row = 2 * oyl + ky;          // iy = 2*oy-1+ky -> yy = 2*oyl+ky
                const float4* ip = reinterpret_cast<const float4*>(
                    &in_s[(ci * 35 + row) * S2_IW + (xg << 4)]);
                float4 a0 = ip[0], a1 = ip[1], a2 = ip[2], a3 = ip[3], a4 = ip[4], a5 = ip[5];
                float iv[24] = {a0.x,a0.y,a0.z,a0.w, a1.x,a1.y,a1.z,a1.w,
                                a2.x,a2.y,a2.z,a2.w, a3.x,a3.y,a3.z,a3.w,
                                a4.x,a4.y,a4.z,a4.w, a5.x,a5.y,a5.z,a5.w};
                #pragma unroll
                for (int kx = 0; kx < 5; ++kx){
                    const float4* wq = reinterpret_cast<const float4*>(
                        &w_s[((ci * 25) + ky * 5 + kx) * 32 + (cg << 3)]);
                    float4 w0 = wq[0], w1 = wq[1];
                    float wv[8] = {w0.x,w0.y,w0.z,w0.w, w1.x,w1.y,w1.z,w1.w};
                    #pragma unroll
                    for (int c = 0; c < 8; ++c)
                        #pragma unroll
                        for (int p = 0; p < 8; ++p)
                            acc[c][p] = fmaf(wv[c], iv[2 * p + kx + 3], acc[c][p]);
                }
            }
        }
    }
    // write out [n][128][32][32], ReLU
    const int obase = ((n * HDIM + cob + (cg << 3)) << 10) + (oy << 5) + (xg << 3);
    #pragma unroll
    for (int c = 0; c < 8; ++c){
        float4 o0 = {fmaxf(acc[c][0],0.f), fmaxf(acc[c][1],0.f), fmaxf(acc[c][2],0.f), fmaxf(acc[c][3],0.f)};
        float4 o1 = {fmaxf(acc[c][4],0.f), fmaxf(acc[c][5],0.f), fmaxf(acc[c][6],0.f), fmaxf(acc[c][7],0.f)};
        *reinterpret_cast<float4*>(out + obase + (c << 10)) = o0;
        *reinterpret_cast<float4*>(out + obase + (c << 10) + 4) = o1;
    }
}

// ---------------- tiled 5x5 stride-1 SAME conv, 256 out channels, 32x32 spatial
// out[n,256,32,32] = (init ? init : bias) + conv(s0,w0) + conv(s1,w1)
// block: 256 thr = 2 cg x 128 pg ; thread: 8co x 8px ; block: 16co x full 32x32
// grid: (16 co-blocks, 32 n). C0, C1 must be multiples of 4. w pointers pre-offset
// to the first channel; per-co stride in floats = wstr.
__global__ __launch_bounds__(256) void conv5s1_k(const float* __restrict__ s0, int C0,
                                                 const float* __restrict__ w0, int w0str,
                                                 const float* __restrict__ s1, int C1,
                                                 const float* __restrict__ w1, int w1str,
                                                 const float* __restrict__ init,
                                                 const float* __restrict__ bias,
                                                 float* __restrict__ out){
    __shared__ float in_s[4 * 36 * 44];      // 4ci x 36 rows x 44 (cols: ix+4, ix in [-4..39])
    __shared__ float w_s[4 * 25 * 16];       // [ci][tap][co16]
    const int cob = blockIdx.x * 16;
    const int n   = blockIdx.y;
    const int tid = threadIdx.x;
    const int cg  = tid >> 7;                // 0..1
    const int hr  = tid & 127;
    const int oy  = hr >> 2;                 // 0..31
    const int xg  = hr & 3;                  // 8 px each

    const int obase = ((n * 256 + cob + (cg << 3)) << 10) + (oy << 5) + (xg << 3);

    float acc[8][8];
    if (init != nullptr){
        #pragma unroll
        for (int c = 0; c < 8; ++c){
            const float4* q = reinterpret_cast<const float4*>(init + obase + (c << 10));
            float4 v0 = q[0], v1 = q[1];
            acc[c][0]=v0.x; acc[c][1]=v0.y; acc[c][2]=v0.z; acc[c][3]=v0.w;
            acc[c][4]=v1.x; acc[c][5]=v1.y; acc[c][6]=v1.z; acc[c][7]=v1.w;
        }
    } else {
        #pragma unroll
        for (int c = 0; c < 8; ++c){
            float b = bias[cob + (cg << 3) + c];
            #pragma unroll
            for (int p = 0; p < 8; ++p) acc[c][p] = b;
        }
    }

    const int nch = C0 + C1;
    for (int cb = 0; cb < nch; cb += 4){
        const float* sp; const float* wp; int wstr; int cl;
        if (cb < C0){ sp = s0 + (size_t)n * C0 * 1024; wp = w0; wstr = w0str; cl = cb; }
        else        { sp = s1 + (size_t)n * C1 * 1024; wp = w1; wstr = w1str; cl = cb - C0; }
        __syncthreads();
        // stage input chunk: rows yy <-> iy = yy-2 ; cols xx <-> ix = xx-4
        for (int idx = tid; idx < 4 * 36 * 44; idx += 256){
            int ci = idx / (36 * 44); int r = idx - ci * (36 * 44);
            int yy = r / 44, xx = r - yy * 44;
            int iy = yy - 2, ix = xx - 4;
            float v = 0.f;
            if ((unsigned)iy < 32u && (unsigned)ix < 32u)
                v = sp[((cl + ci) << 10) + (iy << 5) + ix];
            in_s[idx] = v;
        }
        // stage weights transposed: [ci][tap][co16]
        for (int idx = tid; idx < 4 * 25 * 16; idx += 256){
            int ci = idx / 400; int r = idx - ci * 400;
            int tap = r >> 4; int col = r & 15;
            w_s[idx] = wp[(cob + col) * wstr + (cl + ci) * 25 + tap];
        }
        __syncthreads();
        #pragma unroll
        for (int ci = 0; ci < 4; ++ci){
            #pragma unroll
            for (int ky = 0; ky < 5; ++ky){
                const float4* ip = reinterpret_cast<const float4*>(
                    &in_s[(ci * 36 + oy + ky) * 44 + (xg << 3)]);
                float4 a0 = ip[0], a1 = ip[1], a2 = ip[2], a3 = ip[3];
                float iv[16] = {a0.x,a0.y,a0.z,a0.w, a1.x,a1.y,a1.z,a1.w,
                                a2.x,a2.y,a2.z,a2.w, a3.x,a3.y,a3.z,a3.w};
                #pragma unroll
                for (int kx = 0; kx < 5; ++kx){
                    const float4* wq = reinterpret_cast<const float4*>(
                        &w_s[((ci * 25) + ky * 5 + kx) * 16 + (cg << 3)]);
                    float4 w0v = wq[0], w1v = wq[1];
                    float wv[8] = {w0v.x,w0v.y,w0v.z,w0v.w, w1v.x,w1v.y,w1v.z,w1v.w};
                    #pragma unroll
                    for (int c = 0; c < 8; ++c)
                        #pragma unroll
                        for (int p = 0; p < 8; ++p)
                            acc[c][p] = fmaf(wv[c], iv[p + kx + 2], acc[c][p]);
                }
            }
        }
    }
    #pragma unroll
    for (int c = 0; c < 8; ++c){
        float4 o0 = {acc[c][0], acc[c][1], acc[c][2], acc[c][3]};
        float4 o1 = {acc[c][4], acc[c][5], acc[c][6], acc[c][7]};
        *reinterpret_cast<float4*>(out + obase + (c << 10)) = o0;
        *reinterpret_cast<float4*>(out + obase + (c << 10) + 4) = o1;
    }
}

// ---------------- gauss head: 1x1 conv 128->64 (mu | logvar), z = mu + s*eps, KL vs N(0,1)
__global__ __launch_bounds__(256) void gauss_k(const float* __restrict__ h,
                                               const float* __restrict__ Wg,
                                               const float* __restrict__ bg,
                                               const float* __restrict__ eps0,
                                               float* __restrict__ z0,
                                               float* __restrict__ kl_out){
    __shared__ float w[64 * 128];
    int flat = blockIdx.x * 256 + threadIdx.x;   // [n][zc][pix], 32*32*1024
    int pix = flat & 1023, zc = (flat >> 10) & 31, n = flat >> 15;
    for (int i = threadIdx.x; i < 64 * 128; i += 256) w[i] = Wg[i];
    __syncthreads();
    const float* hb = h + n * HDIM * 1024 + pix;
    float amu = bg[zc], alv = bg[zc + 32];
    for (int ci = 0; ci < HDIM; ++ci){
        float hv = hb[ci << 10];
        amu += hv * w[zc * 128 + ci];
        alv += hv * w[(zc + 32) * 128 + ci];
    }
    float s = softplusf(alv + 0.5f) + 1e-8f;
    z0[flat] = amu + s * eps0[flat];
    float kl = -logf(s) + 0.5f * (s * s + amu * amu) - 0.5f;
    kl_out[flat * KSTEPS + 0] = kl;
}

// ---------------- LSTM pointwise update (in-place on c,h)
__global__ __launch_bounds__(256) void lstm_k(const float* __restrict__ gates,
                                              float* __restrict__ c, float* __restrict__ h){
    int flat = blockIdx.x * 256 + threadIdx.x;   // [n][ch<64][pix]: 32*64*1024
    int pix = flat & 1023, ch = (flat >> 10) & 63, n = flat >> 16;
    const float* gb = gates + ((n * 256 + ch) << 10) + pix;
    float ig = gb[0];
    float fg = gb[64 << 10];
    float gg = gb[128 << 10];
    float og = gb[192 << 10];
    float cv = c[flat];
    float c2 = sigmoidf(fg) * cv + sigmoidf(ig) * tanhf(gg);
    float h2 = sigmoidf(og) * tanhf(c2);
    c[flat] = c2;
    h[flat] = h2;
}

// ---------------- postlin: 1x1 conv 64->64 on h_q; z = mu + s*eps; save mu,s
__global__ __launch_bounds__(256) void postlin_k(const float* __restrict__ hq,
                                                 const float* __restrict__ Wl,
                                                 const float* __restrict__ bl,
                                                 const float* __restrict__ eps_s,
                                                 float* __restrict__ z_out,
                                                 float* __restrict__ qmu, float* __restrict__ qs){
    __shared__ float w[64 * 64];
    int flat = blockIdx.x * 256 + threadIdx.x;   // [n][zc][pix]
    int pix = flat & 1023, zc = (flat >> 10) & 31, n = flat >> 15;
    for (int i = threadIdx.x; i < 64 * 64; i += 256) w[i] = Wl[i];
    __syncthreads();
    const float* hb = hq + ((n * 64) << 10) + pix;
    float amu = bl[zc], alv = bl[zc + 32];
    for (int ci = 0; ci < 64; ++ci){
        float hv = hb[ci << 10];
        amu += hv * w[zc * 64 + ci];
        alv += hv * w[(zc + 32) * 64 + ci];
    }
    float s = softplusf(alv + 0.5f) + 1e-8f;
    z_out[flat] = amu + s * eps_s[flat];
    qmu[flat] = amu;
    qs[flat] = s;
}

// ---------------- priorlin + KL
__global__ __launch_bounds__(256) void priorlin_k(const float* __restrict__ hp,
                                                  const float* __restrict__ Wl,
                                                  const float* __restrict__ bl,
                                                  const float* __restrict__ qmu,
                                                  const float* __restrict__ qs,
                                                  float* __restrict__ kl_out, int step){
    __shared__ float w[64 * 64];
    int flat = blockIdx.x * 256 + threadIdx.x;
    int pix = flat & 1023, zc = (flat >> 10) & 31, n = flat >> 15;
    for (int i = threadIdx.x; i < 64 * 64; i += 256) w[i] = Wl[i];
    __syncthreads();
    const float* hb = hp + ((n * 64) << 10) + pix;
    float amu = bl[zc], alv = bl[zc + 32];
    for (int ci = 0; ci < 64; ++ci){
        float hv = hb[ci << 10];
        amu += hv * w[zc * 64 + ci];
        alv += hv * w[(zc + 32) * 64 + ci];
    }
    float ps = softplusf(alv + 0.5f) + 1e-8f;
    float qm = qmu[flat], q = qs[flat];
    float d = qm - amu;
    float kl = logf(ps / q) + (q * q + d * d) / (2.f * ps * ps) - 0.5f;
    kl_out[flat * KSTEPS + step] = kl;
}

// ---------------- dec1: conv_transpose 4x4 stride 2 SAME, 32->128, 32x32 -> 64x64, ReLU
__global__ __launch_bounds__(256) void dec1_k(const float* __restrict__ z,
                                              const float* __restrict__ Wt,
                                              const float* __restrict__ bias,
                                              float* __restrict__ out){
    __shared__ float w[ZDIM * 16]; // 512
    int flat = blockIdx.x * 256 + threadIdx.x;   // [n][co][oy][ox] 32*128*64*64
    int ox = flat & 63, oy = (flat >> 6) & 63, co = (flat >> 12) & 127, n = flat >> 19;
    for (int i = threadIdx.x; i < ZDIM * 16; i += 256) w[i] = Wt[co * ZDIM * 16 + i];
    __syncthreads();
    float acc = bias[co];
    const float* zb = z + ((n * ZDIM) << 10);
    #pragma unroll
    for (int ky = 0; ky < 4; ++ky){
        int t = oy - 2 + ky;
        if (t & 1) continue;                      // lhs-dilation parity
        int iy = t >> 1;
        if ((unsigned)iy >= 32u) continue;
        #pragma unroll
        for (int kx = 0; kx < 4; ++kx){
            int tx = ox - 2 + kx;
            if (tx & 1) continue;
            int ix = tx >> 1;
            if ((unsigned)ix >= 32u) continue;
            const float* zp = zb + (iy << 5) + ix;
            const float* wp = w + ky * 4 + kx;
            for (int ci = 0; ci < ZDIM; ++ci){
                acc += zp[ci << 10] * wp[ci * 16];
            }
        }
    }
    out[flat] = fmaxf(acc, 0.f);
}

// ---------------- dec2: conv_transpose 4x4 stride 2 SAME, 128->1, 64x64 -> 128x128
__global__ __launch_bounds__(256) void dec2_k(const float* __restrict__ a,
                                              const float* __restrict__ Wt,
                                              const float* __restrict__ bias,
                                              float* __restrict__ out){
    __shared__ float w[HDIM * 16]; // 2048
    int flat = blockIdx.x * 256 + threadIdx.x;   // [n][oy][ox] 32*128*128
    int ox = flat & 127, oy = (flat >> 7) & 127, n = flat >> 14;
    for (int i = threadIdx.x; i < HDIM * 16; i += 256) w[i] = Wt[i];
    __syncthreads();
    float acc = bias[0];
    const float* ab = a + n * HDIM * 4096;
    #pragma unroll
    for (int ky = 0; ky < 4; ++ky){
        int t = oy - 2 + ky;
        if (t & 1) continue;
        int iy = t >> 1;
        if ((unsigned)iy >= 64u) continue;
        #pragma unroll
        for (int kx = 0; kx < 4; ++kx){
            int tx = ox - 2 + kx;
            if (tx & 1) continue;
            int ix = tx >> 1;
            if ((unsigned)ix >= 64u) continue;
            const float* ap = ab + (iy << 6) + ix;
            const float* wp = w + ky * 4 + kx;
            for (int ci = 0; ci < HDIM; ++ci){
                acc += ap[ci << 12] * wp[ci * 16];
            }
        }
    }
    out[flat] = acc;
}

// ---------------- stick-breaking accumulation over K decoder outputs
__global__ __launch_bounds__(256) void stick_k(const float* __restrict__ dec,
                                               float* __restrict__ lm){
    int flat = blockIdx.x * 256 + threadIdx.x;   // [n][pix] 32*16384
    float ss = 0.f;
    #pragma unroll
    for (int k = 0; k < KSTEPS; ++k){
        float v = dec[k * (BATCH * 16384) + flat];
        if (k < KSTEPS - 1){
            lm[k * (BATCH * 16384) + flat] = ss + logsigf(v);
            ss += logsigf(-v);
        } else {
            lm[k * (BATCH * 16384) + flat] = ss + logsigf(v);
        }
    }
}

extern "C" void kernel_launch(void* const* d_in, const int* in_sizes, int n_in,
                              void* d_out, int out_size, void* d_ws, size_t ws_size,
                              hipStream_t stream){
    const float* x        = (const float*)d_in[0];
    const float* eps      = (const float*)d_in[1];
    const float* stem1_W  = (const float*)d_in[2];
    const float* stem1_b  = (const float*)d_in[3];
    const float* stem2_W  = (const float*)d_in[4];
    const float* stem2_b  = (const float*)d_in[5];
    const float* gauss_W  = (const float*)d_in[6];
    const float* gauss_b  = (const float*)d_in[7];
    const float* post_Wx  = (const float*)d_in[8];
    const float* post_Wh  = (const float*)d_in[9];
    const float* post_b   = (const float*)d_in[10];
    const float* postlin_W= (const float*)d_in[11];
    const float* postlin_b= (const float*)d_in[12];
    const float* prior_Wx = (const float*)d_in[13];
    const float* prior_Wh = (const float*)d_in[14];
    const float* prior_b  = (const float*)d_in[15];
    const float* priorlin_W=(const float*)d_in[16];
    const float* priorlin_b=(const float*)d_in[17];
    const float* dec1_W   = (const float*)d_in[18];
    const float* dec1_b   = (const float*)d_in[19];
    const float* dec2_W   = (const float*)d_in[20];
    const float* dec2_b   = (const float*)d_in[21];

    float* lm_out = (float*)d_out;                         // [6,32,1,128,128]
    float* kl_out = lm_out + KSTEPS * BATCH * 16384;       // [32,32,32,32,6]

    float* p = (float*)d_ws;
    float* h1    = p; p += (size_t)BATCH * HDIM * 64 * 64;   // 16,777,216 (stem1 out / dec1 tmp / pregates alias)
    float* h2    = p; p += (size_t)BATCH * HDIM * 32 * 32;   //  4,194,304
    float* zs    = p; p += (size_t)KSTEPS * BATCH * ZDIM * 1024; // 6,291,456
    float* cq    = p; p += (size_t)BATCH * 64 * 1024;        //  2,097,152
    float* hq    = p; p += (size_t)BATCH * 64 * 1024;
    float* cp    = p; p += (size_t)BATCH * 64 * 1024;
    float* hp    = p; p += (size_t)BATCH * 64 * 1024;
    float* gates = p; p += (size_t)BATCH * 256 * 1024;       //  8,388,608
    float* qmu   = p; p += (size_t)BATCH * ZDIM * 1024;
    float* qs    = p; p += (size_t)BATCH * ZDIM * 1024;
    float* dco   = p; p += (size_t)KSTEPS * BATCH * 16384;   //  3,145,728

    // pregates [32,256,1024] aliases h1: h1's stem data is dead after stem2,
    // and dec1 (which reuses h1) runs only after the last step consumed pregates.
    float* pregates = h1;

    // zero LSTM states (cq,hq,cp,hp contiguous)
    hipMemsetAsync(cq, 0, (size_t)4 * BATCH * 64 * 1024 * sizeof(float), stream);

    stem1_k<<<65536, 256, 0, stream>>>(x, stem1_W, stem1_b, h1);
    conv5s2_k<<<dim3(4, 2, 32), 256, 0, stream>>>(h1, stem2_W, stem2_b, h2);
    gauss_k<<<4096, 256, 0, stream>>>(h2, gauss_W, gauss_b, eps, zs, kl_out);

    // one-time: pregates = bias + conv(h2, post_Wx[:, :128])   (h2 constant across steps)
    conv5s1_k<<<dim3(16, 32), 256, 0, stream>>>(
        h2, 128, post_Wx, 160 * 25,
        (const float*)nullptr, 0, (const float*)nullptr, 0,
        (const float*)nullptr, post_b, pregates);

    for (int s = 0; s < KSTEPS - 1; ++s){
        const float* zprev = zs + (size_t)s * 1048576;
        // posterior gates = pregates + conv(z, post_Wx[:, 128:]) + conv(hq, post_Wh)
        conv5s1_k<<<dim3(16, 32), 256, 0, stream>>>(
            zprev, 32, post_Wx + 128 * 25, 160 * 25,
            hq, 64, post_Wh, 64 * 25,
            pregates, post_b, gates);
        lstm_k<<<8192, 256, 0, stream>>>(gates, cq, hq);
        postlin_k<<<4096, 256, 0, stream>>>(hq, postlin_W, postlin_b,
                                            eps + (size_t)(s + 1) * 1048576,
                                            zs + (size_t)(s + 1) * 1048576, qmu, qs);
        // prior gates = bias + conv(z, prior_Wx) + conv(hp, prior_Wh)
        conv5s1_k<<<dim3(16, 32), 256, 0, stream>>>(
            zprev, 32, prior_Wx, 32 * 25,
            hp, 64, prior_Wh, 64 * 25,
            (const float*)nullptr, prior_b, gates);
        lstm_k<<<8192, 256, 0, stream>>>(gates, cp, hp);
        priorlin_k<<<4096, 256, 0, stream>>>(hp, priorlin_W, priorlin_b, qmu, qs, kl_out, s + 1);
    }

    for (int k = 0; k < KSTEPS; ++k){
        dec1_k<<<65536, 256, 0, stream>>>(zs + (size_t)k * 1048576, dec1_W, dec1_b, h1);
        dec2_k<<<2048, 256, 0, stream>>>(h1, dec2_W, dec2_b, dco + (size_t)k * BATCH * 16384);
    }
    stick_k<<<2048, 256, 0, stream>>>(dco, lm_out);
}

// Round 4
// 4691.304 us; speedup vs baseline: 18.6829x; 2.5720x over previous
//
#include <hip/hip_runtime.h>
#include <math.h>

#define BATCH 32
#define HDIM 128
#define ZDIM 32
#define KSTEPS 6

typedef unsigned short ushort_t;
using bf16x8 = __attribute__((ext_vector_type(8))) short;
using f32x4v = __attribute__((ext_vector_type(4))) float;

__device__ __forceinline__ float softplusf(float x){
    return fmaxf(x, 0.f) + log1pf(expf(-fabsf(x)));
}
__device__ __forceinline__ float sigmoidf(float x){
    return 1.f / (1.f + expf(-x));
}
__device__ __forceinline__ float logsigf(float x){
    return fminf(x, 0.f) - log1pf(expf(-fabsf(x)));
}
__device__ __forceinline__ float bf2f(ushort_t u){
    return __uint_as_float(((unsigned)u) << 16);
}
__device__ __forceinline__ ushort_t f2bf(float f){
    unsigned x = __float_as_uint(f);
    unsigned r = (x + 0x7fffu + ((x >> 16) & 1u)) >> 16;
    return (ushort_t)r;
}

// ---------------- stem1: conv 5x5 stride 2, 3->128, 128x128 -> 64x64, ReLU
__global__ __launch_bounds__(256) void stem1_k(const float* __restrict__ x,
                                               const float* __restrict__ Wt,
                                               const float* __restrict__ bias,
                                               float* __restrict__ out){
    __shared__ float w[75];
    int flat = blockIdx.x * 256 + threadIdx.x;
    int ox = flat & 63, oy = (flat >> 6) & 63, co = (flat >> 12) & 127, n = flat >> 19;
    if (threadIdx.x < 75) w[threadIdx.x] = Wt[co * 75 + threadIdx.x];
    __syncthreads();
    float acc = bias[co];
    const float* xb = x + n * 3 * 128 * 128;
    for (int ci = 0; ci < 3; ++ci){
        const float* xc = xb + (ci << 14);
        const float* wc = w + ci * 25;
        #pragma unroll
        for (int ky = 0; ky < 5; ++ky){
            int iy = oy * 2 - 1 + ky;
            if ((unsigned)iy >= 128u) continue;
            const float* xr = xc + (iy << 7);
            #pragma unroll
            for (int kx = 0; kx < 5; ++kx){
                int ix = ox * 2 - 1 + kx;
                if ((unsigned)ix >= 128u) continue;
                acc += xr[ix] * wc[ky * 5 + kx];
            }
        }
    }
    out[flat] = fmaxf(acc, 0.f);
}

// ---------------- stem2: conv 5x5 stride 2 SAME, 128->128, 64x64 -> 32x32, ReLU (tiled f32)
#define S2_IW 76
__global__ __launch_bounds__(256) void conv5s2_k(const float* __restrict__ in,
                                                 const float* __restrict__ Wt,
                                                 const float* __restrict__ bias,
                                                 float* __restrict__ out){
    __shared__ float in_s[4 * 35 * S2_IW];
    __shared__ float w_s[4 * 25 * 32];
    const int cob = blockIdx.x * 32;
    const int yh  = blockIdx.y;
    const int n   = blockIdx.z;
    const int tid = threadIdx.x;
    const int cg  = tid >> 6;
    const int pg  = tid & 63;
    const int oyl = pg >> 2;
    const int xg  = pg & 3;
    const int oy  = yh * 16 + oyl;

    float acc[8][8];
    #pragma unroll
    for (int c = 0; c < 8; ++c){
        float b = bias[cob + cg * 8 + c];
        #pragma unroll
        for (int p = 0; p < 8; ++p) acc[c][p] = b;
    }

    const float* ib = in + (size_t)n * HDIM * 4096;
    for (int cb = 0; cb < HDIM; cb += 4){
        __syncthreads();
        for (int idx = tid; idx < 4 * 35 * S2_IW; idx += 256){
            int ci = idx / (35 * S2_IW); int r = idx - ci * (35 * S2_IW);
            int yy = r / S2_IW, xx = r - yy * S2_IW;
            int iy = 32 * yh - 1 + yy, ix = xx - 4;
            float v = 0.f;
            if ((unsigned)iy < 64u && (unsigned)ix < 64u)
                v = ib[((cb + ci) << 12) + (iy << 6) + ix];
            in_s[idx] = v;
        }
        for (int idx = tid; idx < 4 * 25 * 32; idx += 256){
            int ci = idx / 800; int r = idx - ci * 800;
            int tap = r >> 5; int col = r & 31;
            w_s[idx] = Wt[(cob + col) * (HDIM * 25) + (cb + ci) * 25 + tap];
        }
        __syncthreads();
        #pragma unroll
        for (int ci = 0; ci < 4; ++ci){
            #pragma unroll
            for (int ky = 0; ky < 5; ++ky){
                int row = 2 * oyl + ky;
                const float4* ip = reinterpret_cast<const float4*>(
                    &in_s[(ci * 35 + row) * S2_IW + (xg << 4)]);
                float4 a0 = ip[0], a1 = ip[1], a2 = ip[2], a3 = ip[3], a4 = ip[4], a5 = ip[5];
                float iv[24] = {a0.x,a0.y,a0.z,a0.w, a1.x,a1.y,a1.z,a1.w,
                                a2.x,a2.y,a2.z,a2.w, a3.x,a3.y,a3.z,a3.w,
                                a4.x,a4.y,a4.z,a4.w, a5.x,a5.y,a5.z,a5.w};
                #pragma unroll
                for (int kx = 0; kx < 5; ++kx){
                    const float4* wq = reinterpret_cast<const float4*>(
                        &w_s[((ci * 25) + ky * 5 + kx) * 32 + (cg << 3)]);
                    float4 w0 = wq[0], w1 = wq[1];
                    float wv[8] = {w0.x,w0.y,w0.z,w0.w, w1.x,w1.y,w1.z,w1.w};
                    #pragma unroll
                    for (int c = 0; c < 8; ++c)
                        #pragma unroll
                        for (int p = 0; p < 8; ++p)
                            acc[c][p] = fmaf(wv[c], iv[2 * p + kx + 3], acc[c][p]);
                }
            }
        }
    }
    const int obase = ((n * HDIM + cob + (cg << 3)) << 10) + (oy << 5) + (xg << 3);
    #pragma unroll
    for (int c = 0; c < 8; ++c){
        float4 o0 = {fmaxf(acc[c][0],0.f), fmaxf(acc[c][1],0.f), fmaxf(acc[c][2],0.f), fmaxf(acc[c][3],0.f)};
        float4 o1 = {fmaxf(acc[c][4],0.f), fmaxf(acc[c][5],0.f), fmaxf(acc[c][6],0.f), fmaxf(acc[c][7],0.f)};
        *reinterpret_cast<float4*>(out + obase + (c << 10)) = o0;
        *reinterpret_cast<float4*>(out + obase + (c << 10) + 4) = o1;
    }
}

// ---------------- h2 NCHW f32 -> NHWC bf16
__global__ __launch_bounds__(256) void h2n_k(const float* __restrict__ h2,
                                             ushort_t* __restrict__ dst){
    int t = blockIdx.x * 256 + threadIdx.x;        // [n][pix], 32768
    int pix = t & 1023, n = t >> 10;
    const float* s = h2 + ((size_t)n << 17) + pix;
    ushort_t* d = dst + ((size_t)t << 7);
    for (int ci = 0; ci < 128; ++ci) d[ci] = f2bf(s[(size_t)ci << 10]);
}

// ---------------- weight convert: OIHW f32 -> [tap][ck][co256][ci32] bf16
__global__ __launch_bounds__(256) void cvtw_k(const float* __restrict__ src,
                                              ushort_t* __restrict__ dst,
                                              int Cfull, int ci_off, int ncs,
                                              int ck_off, int NCHK){
    int idx = blockIdx.x * 256 + threadIdx.x;
    int total = 25 * ncs * 8192;
    if (idx >= total) return;
    int tap = idx / (ncs * 8192);
    int r = idx - tap * (ncs * 8192);
    int ckl = r >> 13;
    int r2 = r & 8191;
    int co = r2 >> 5, cl = r2 & 31;
    float v = src[((size_t)co * Cfull + ci_off + (ckl << 5) + cl) * 25 + tap];
    dst[((((size_t)tap * NCHK + ck_off + ckl) << 8) + co) * 32 + cl] = f2bf(v);
}

// ---------------- dec1 weight transpose: [co128][ci32][16] -> [ci32][tap16][co128]
__global__ __launch_bounds__(256) void dec1wt_k(const float* __restrict__ W,
                                                float* __restrict__ Wo){
    int idx = blockIdx.x * 256 + threadIdx.x;      // 65536
    int co = idx & 127, tap = (idx >> 7) & 15, ci = idx >> 11;
    Wo[idx] = W[(co << 9) + (ci << 4) + tap];
}

// ---------------- MFMA gate conv: 5x5 SAME over 32x32, 256 out ch, bf16 NHWC inputs
// out[n,256,32,32] f32 = (init ? init : bias) + conv(in0[C0],w) + conv(in1[C1],w)
// grid (16 px-blocks of 64px = 2 rows, 32 n); 256 thr = 4 waves x 64co
#define GCP 104   // padded LDS channel stride (208B: 8-phase bank spread)
__global__ __launch_bounds__(256) void gconv_k(
    const ushort_t* __restrict__ in0, int C0, int str0,
    const ushort_t* __restrict__ in1, int C1, int str1,
    const ushort_t* __restrict__ wb, int NCHK,
    const float* __restrict__ initp, const float* __restrict__ bias,
    float* __restrict__ outp)
{
    extern __shared__ ushort_t sm[];               // [6 rows][36 cols][GCP]
    const int pb = blockIdx.x, n = blockIdx.y;
    const int tid = threadIdx.x, lane = tid & 63, wv = tid >> 6;
    const int Ct = C0 + C1;
    const int nch8 = Ct >> 3;
    for (int idx = tid; idx < 216 * nch8; idx += 256){
        int cell = idx / nch8;
        int c8 = (idx - cell * nch8) << 3;
        int rr = cell / 36, cc = cell - rr * 36;
        int y = pb * 2 - 2 + rr, x = cc - 2;
        bf16x8 v = {0,0,0,0,0,0,0,0};
        if ((unsigned)y < 32u && (unsigned)x < 32u){
            int pix = (y << 5) + x;
            if (c8 < C0) v = *(const bf16x8*)(in0 + ((size_t)((n << 10) + pix)) * str0 + c8);
            else         v = *(const bf16x8*)(in1 + ((size_t)((n << 10) + pix)) * str1 + (c8 - C0));
        }
        *(bf16x8*)(sm + cell * GCP + c8) = v;
    }
    __syncthreads();

    const int wbase = wv << 6;
    const int lm = lane & 15, lg = lane >> 4;
    f32x4v z4 = {0.f, 0.f, 0.f, 0.f};
    f32x4v acc[4][4];
    #pragma unroll
    for (int f = 0; f < 4; ++f)
        #pragma unroll
        for (int cf = 0; cf < 4; ++cf) acc[f][cf] = z4;

    int ky = 0, kx = 0;
    for (int tap = 0; tap < 25; ++tap){
        for (int ck = 0; ck < NCHK; ++ck){
            bf16x8 a[4];
            #pragma unroll
            for (int f = 0; f < 4; ++f){
                int rr = (f >> 1) + ky;
                int cc = ((f & 1) << 4) + lm + kx;
                a[f] = *(const bf16x8*)(sm + (rr * 36 + cc) * GCP + (ck << 5) + (lg << 3));
            }
            const ushort_t* wp = wb + ((size_t)((((tap * NCHK + ck) << 8) + wbase + lm)) << 5) + (lg << 3);
            #pragma unroll
            for (int cf = 0; cf < 4; ++cf){
                bf16x8 b = *(const bf16x8*)(wp + (cf << 9));
                #pragma unroll
                for (int f = 0; f < 4; ++f)
                    acc[f][cf] = __builtin_amdgcn_mfma_f32_16x16x32_bf16(a[f], b, acc[f][cf], 0, 0, 0);
            }
        }
        if (++kx == 5){ kx = 0; ++ky; }
    }

    #pragma unroll
    for (int f = 0; f < 4; ++f){
        int px = (pb << 6) + (f << 4) + (lg << 2);
        #pragma unroll
        for (int cf = 0; cf < 4; ++cf){
            int co = wbase + (cf << 4) + lm;
            size_t o = (((size_t)n * 256 + co) << 10) + px;
            f32x4v r = acc[f][cf];
            if (initp){
                float4 iv = *(const float4*)(initp + o);
                r[0] += iv.x; r[1] += iv.y; r[2] += iv.z; r[3] += iv.w;
            } else {
                float b = bias[co];
                r[0] += b; r[1] += b; r[2] += b; r[3] += b;
            }
            float4 st = {r[0], r[1], r[2], r[3]};
            *(float4*)(outp + o) = st;
        }
    }
}

// ---------------- LSTM pointwise (gates f32 NCHW; c f32; h written as NHWC bf16)
__global__ __launch_bounds__(256) void lstm_k(const float* __restrict__ gates,
                                              float* __restrict__ c,
                                              ushort_t* __restrict__ hn){
    int flat = blockIdx.x * 256 + threadIdx.x;     // [n][ch64][pix]
    int pix = flat & 1023, ch = (flat >> 10) & 63, n = flat >> 16;
    const float* gb = gates + (((size_t)n * 256 + ch) << 10) + pix;
    float ig = gb[0];
    float fg = gb[64 << 10];
    float gg = gb[128 << 10];
    float og = gb[192 << 10];
    float cv = c[flat];
    float c2 = sigmoidf(fg) * cv + sigmoidf(ig) * tanhf(gg);
    float h2 = sigmoidf(og) * tanhf(c2);
    c[flat] = c2;
    hn[((((size_t)n << 10) + pix) << 6) + ch] = f2bf(h2);
}

// ---------------- gauss head: 1x1 conv 128->64 on f32 h2; z (f32 + NHWC bf16), KL vs N(0,1)
__global__ __launch_bounds__(256) void gauss_k(const float* __restrict__ h,
                                               const float* __restrict__ Wg,
                                               const float* __restrict__ bg,
                                               const float* __restrict__ eps0,
                                               float* __restrict__ z0,
                                               ushort_t* __restrict__ zn,
                                               float* __restrict__ kl_out){
    __shared__ float w[64 * 128];
    int flat = blockIdx.x * 256 + threadIdx.x;     // [n][zc][pix]
    int pix = flat & 1023, zc = (flat >> 10) & 31, n = flat >> 15;
    for (int i = threadIdx.x; i < 64 * 128; i += 256) w[i] = Wg[i];
    __syncthreads();
    const float* hb = h + (size_t)n * HDIM * 1024 + pix;
    float amu = bg[zc], alv = bg[zc + 32];
    for (int ci = 0; ci < HDIM; ++ci){
        float hv = hb[(size_t)ci << 10];
        amu += hv * w[zc * 128 + ci];
        alv += hv * w[(zc + 32) * 128 + ci];
    }
    float s = softplusf(alv + 0.5f) + 1e-8f;
    float z = amu + s * eps0[flat];
    z0[flat] = z;
    zn[((((size_t)n << 10) + pix) << 5) + zc] = f2bf(z);
    float kl = -logf(s) + 0.5f * (s * s + amu * amu) - 0.5f;
    kl_out[(size_t)flat * KSTEPS + 0] = kl;
}

// ---------------- postlin: 1x1 conv 64->64 on NHWC bf16 h_q; z = mu + s*eps
__global__ __launch_bounds__(256) void postlin_k(const ushort_t* __restrict__ hq,
                                                 const float* __restrict__ Wl,
                                                 const float* __restrict__ bl,
                                                 const float* __restrict__ eps_s,
                                                 float* __restrict__ z_out,
                                                 ushort_t* __restrict__ zn,
                                                 float* __restrict__ qmu, float* __restrict__ qs){
    __shared__ float w[64 * 64];
    int flat = blockIdx.x * 256 + threadIdx.x;
    int pix = flat & 1023, zc = (flat >> 10) & 31, n = flat >> 15;
    for (int i = threadIdx.x; i < 64 * 64; i += 256) w[i] = Wl[i];
    __syncthreads();
    const ushort_t* hb = hq + ((((size_t)n << 10) + pix) << 6);
    float amu = bl[zc], alv = bl[zc + 32];
    for (int ci = 0; ci < 64; ++ci){
        float hv = bf2f(hb[ci]);
        amu += hv * w[zc * 64 + ci];
        alv += hv * w[(zc + 32) * 64 + ci];
    }
    float s = softplusf(alv + 0.5f) + 1e-8f;
    float z = amu + s * eps_s[flat];
    z_out[flat] = z;
    zn[((((size_t)n << 10) + pix) << 5) + zc] = f2bf(z);
    qmu[flat] = amu;
    qs[flat] = s;
}

// ---------------- priorlin + KL (NHWC bf16 h_p)
__global__ __launch_bounds__(256) void priorlin_k(const ushort_t* __restrict__ hp,
                                                  const float* __restrict__ Wl,
                                                  const float* __restrict__ bl,
                                                  const float* __restrict__ qmu,
                                                  const float* __restrict__ qs,
                                                  float* __restrict__ kl_out, int step){
    __shared__ float w[64 * 64];
    int flat = blockIdx.x * 256 + threadIdx.x;
    int pix = flat & 1023, zc = (flat >> 10) & 31, n = flat >> 15;
    for (int i = threadIdx.x; i < 64 * 64; i += 256) w[i] = Wl[i];
    __syncthreads();
    const ushort_t* hb = hp + ((((size_t)n << 10) + pix) << 6);
    float amu = bl[zc], alv = bl[zc + 32];
    for (int ci = 0; ci < 64; ++ci){
        float hv = bf2f(hb[ci]);
        amu += hv * w[zc * 64 + ci];
        alv += hv * w[(zc + 32) * 64 + ci];
    }
    float ps = softplusf(alv + 0.5f) + 1e-8f;
    float qm = qmu[flat], q = qs[flat];
    float d = qm - amu;
    float kl = logf(ps / q) + (q * q + d * d) / (2.f * ps * ps) - 0.5f;
    kl_out[(size_t)flat * KSTEPS + step] = kl;
}

// ---------------- dec1 tiled: conv_transpose 4x4 s2 SAME, 32->128, 32x32 -> 64x64, ReLU
// block: 64co x 16x16 out tile; parity-decomposed taps; grid (2, 16, 32)
__global__ __launch_bounds__(256) void dec1_k(const float* __restrict__ z,
                                              const float* __restrict__ Wt,  // [ci32][tap16][co128]
                                              const float* __restrict__ bias,
                                              float* __restrict__ out){
    __shared__ float zin[32][10][13];
    __shared__ float ws[4][16][64];
    const int cob = blockIdx.x << 6;
    const int ty = blockIdx.y >> 2, tx = blockIdx.y & 3;
    const int n = blockIdx.z;
    const int tid = threadIdx.x;
    const int cg = tid >> 5, pg = tid & 31;
    const int oyl = pg >> 1, xh = pg & 1;
    const int oy = (ty << 4) + oyl;
    const int oxb = (tx << 4) + (xh << 3);

    for (int idx = tid; idx < 3200; idx += 256){
        int ci = idx / 100, r = idx - ci * 100;
        int ry = r / 10, rx = r - ry * 10;
        int iy = (ty << 3) - 1 + ry, ix = (tx << 3) - 1 + rx;
        float v = 0.f;
        if ((unsigned)iy < 32u && (unsigned)ix < 32u)
            v = z[(((size_t)n * 32 + ci) << 10) + (iy << 5) + ix];
        zin[ci][ry][rx] = v;
    }

    float acc[8][8];
    #pragma unroll
    for (int c = 0; c < 8; ++c)
        #pragma unroll
        for (int p = 0; p < 8; ++p) acc[c][p] = 0.f;

    const int py = oy & 1;
    const int ryA = (oyl >> 1) + py;
    const int kyA = py, kyB = py + 2;
    const int xq = xh << 2;

    for (int cb = 0; cb < 32; cb += 4){
        __syncthreads();
        for (int idx = tid; idx < 4096; idx += 256){
            int cl = idx >> 10, r = idx & 1023;
            int tap = r >> 6, co = r & 63;
            ws[cl][tap][co] = Wt[((size_t)(cb + cl) << 11) + (tap << 7) + cob + co];
        }
        __syncthreads();
        #pragma unroll
        for (int cl = 0; cl < 4; ++cl){
            float rvA[6], rvB[6];
            #pragma unroll
            for (int i = 0; i < 6; ++i){
                rvA[i] = zin[cb + cl][ryA][xq + i];
                rvB[i] = zin[cb + cl][ryA + 1][xq + i];
            }
            #pragma unroll
            for (int t = 0; t < 2; ++t){
                const float* rv = t ? rvB : rvA;
                int kyt = t ? kyB : kyA;
                #pragma unroll
                for (int kx = 0; kx < 4; ++kx){
                    int pxp = kx & 1, d = kx >> 1;
                    const float4* q = (const float4*)&ws[cl][(kyt << 2) + kx][cg << 3];
                    float4 w0 = q[0], w1 = q[1];
                    float w8[8] = {w0.x, w0.y, w0.z, w0.w, w1.x, w1.y, w1.z, w1.w};
                    #pragma unroll
                    for (int ph = 0; ph < 4; ++ph){
                        int p = ph * 2 + pxp;
                        float inv = rv[ph + pxp + d];
                        #pragma unroll
                        for (int c = 0; c < 8; ++c)
                            acc[c][p] = fmaf(inv, w8[c], acc[c][p]);
                    }
                }
            }
        }
    }

    #pragma unroll
    for (int c = 0; c < 8; ++c){
        float b = bias[cob + (cg << 3) + c];
        size_t o = (((size_t)n * 128 + cob + (cg << 3) + c) << 12) + (oy << 6) + oxb;
        float4 o0 = {fmaxf(acc[c][0] + b, 0.f), fmaxf(acc[c][1] + b, 0.f),
                     fmaxf(acc[c][2] + b, 0.f), fmaxf(acc[c][3] + b, 0.f)};
        float4 o1 = {fmaxf(acc[c][4] + b, 0.f), fmaxf(acc[c][5] + b, 0.f),
                     fmaxf(acc[c][6] + b, 0.f), fmaxf(acc[c][7] + b, 0.f)};
        *reinterpret_cast<float4*>(out + o) = o0;
        *reinterpret_cast<float4*>(out + o + 4) = o1;
    }
}

// ---------------- dec2: conv_transpose 4x4 s2 SAME, 128->1, 64x64 -> 128x128
__global__ __launch_bounds__(256) void dec2_k(const float* __restrict__ a,
                                              const float* __restrict__ Wt,
                                              const float* __restrict__ bias,
                                              float* __restrict__ out){
    __shared__ float w[HDIM * 16];
    int flat = blockIdx.x * 256 + threadIdx.x;     // [n][oy][ox]
    int ox = flat & 127, oy = (flat >> 7) & 127, n = flat >> 14;
    for (int i = threadIdx.x; i < HDIM * 16; i += 256) w[i] = Wt[i];
    __syncthreads();
    float acc = bias[0];
    const float* ab = a + (size_t)n * HDIM * 4096;
    #pragma unroll
    for (int ky = 0; ky < 4; ++ky){
        int t = oy - 2 + ky;
        if (t & 1) continue;
        int iy = t >> 1;
        if ((unsigned)iy >= 64u) continue;
        #pragma unroll
        for (int kx = 0; kx < 4; ++kx){
            int tx = ox - 2 + kx;
            if (tx & 1) continue;
            int ix = tx >> 1;
            if ((unsigned)ix >= 64u) continue;
            const float* ap = ab + (iy << 6) + ix;
            const float* wp = w + ky * 4 + kx;
            for (int ci = 0; ci < HDIM; ++ci){
                acc += ap[(size_t)ci << 12] * wp[ci * 16];
            }
        }
    }
    out[flat] = acc;
}

// ---------------- stick-breaking over K decoder outputs
__global__ __launch_bounds__(256) void stick_k(const float* __restrict__ dec,
                                               float* __restrict__ lm){
    int flat = blockIdx.x * 256 + threadIdx.x;
    float ss = 0.f;
    #pragma unroll
    for (int k = 0; k < KSTEPS; ++k){
        float v = dec[(size_t)k * (BATCH * 16384) + flat];
        if (k < KSTEPS - 1){
            lm[(size_t)k * (BATCH * 16384) + flat] = ss + logsigf(v);
            ss += logsigf(-v);
        } else {
            lm[(size_t)k * (BATCH * 16384) + flat] = ss + logsigf(v);
        }
    }
}

extern "C" void kernel_launch(void* const* d_in, const int* in_sizes, int n_in,
                              void* d_out, int out_size, void* d_ws, size_t ws_size,
                              hipStream_t stream){
    const float* x        = (const float*)d_in[0];
    const float* eps      = (const float*)d_in[1];
    const float* stem1_W  = (const float*)d_in[2];
    const float* stem1_b  = (const float*)d_in[3];
    const float* stem2_W  = (const float*)d_in[4];
    const float* stem2_b  = (const float*)d_in[5];
    const float* gauss_W  = (const float*)d_in[6];
    const float* gauss_b  = (const float*)d_in[7];
    const float* post_Wx  = (const float*)d_in[8];
    const float* post_Wh  = (const float*)d_in[9];
    const float* post_b   = (const float*)d_in[10];
    const float* postlin_W= (const float*)d_in[11];
    const float* postlin_b= (const float*)d_in[12];
    const float* prior_Wx = (const float*)d_in[13];
    const float* prior_Wh = (const float*)d_in[14];
    const float* prior_b  = (const float*)d_in[15];
    const float* priorlin_W=(const float*)d_in[16];
    const float* priorlin_b=(const float*)d_in[17];
    const float* dec1_W   = (const float*)d_in[18];
    const float* dec1_b   = (const float*)d_in[19];
    const float* dec2_W   = (const float*)d_in[20];
    const float* dec2_b   = (const float*)d_in[21];

    float* lm_out = (float*)d_out;
    float* kl_out = lm_out + (size_t)KSTEPS * BATCH * 16384;

    float* p = (float*)d_ws;
    float* h1    = p; p += (size_t)BATCH * HDIM * 64 * 64;       // 16.78M f (pregates alias / dec1 out)
    float* h2    = p; p += (size_t)BATCH * HDIM * 32 * 32;       // 4.19M f (dco alias)
    float* zs    = p; p += (size_t)KSTEPS * BATCH * ZDIM * 1024; // 6.29M f
    float* cq    = p; p += (size_t)BATCH * 64 * 1024;            // f32 states (zeroed)
    float* cp    = p; p += (size_t)BATCH * 64 * 1024;
    ushort_t* hq_n = (ushort_t*)p; p += (size_t)BATCH * 64 * 1024 / 2;   // bf16 NHWC [n][pix][64]
    ushort_t* hp_n = (ushort_t*)p; p += (size_t)BATCH * 64 * 1024 / 2;
    float* gates = p; p += (size_t)BATCH * 256 * 1024;
    float* qmu   = p; p += (size_t)BATCH * ZDIM * 1024;
    float* qs    = p; p += (size_t)BATCH * ZDIM * 1024;
    ushort_t* z_n  = (ushort_t*)p; p += (size_t)BATCH * ZDIM * 1024 / 2; // bf16 NHWC [n][pix][32]
    ushort_t* h2_n = (ushort_t*)p; p += (size_t)BATCH * HDIM * 1024 / 2; // bf16 NHWC [n][pix][128]
    ushort_t* wbuf = (ushort_t*)p; p += 1048576;                         // 2.097M ushorts
    float* wdec1 = p; p += 65536;                                        // dec1 W transposed

    ushort_t* w_pre0 = wbuf;                 // 25*2*8192 = 409600
    ushort_t* w_pre1 = w_pre0 + 409600;
    ushort_t* w_post = w_pre1 + 409600;      // 25*3*8192 = 614400
    ushort_t* w_prior = w_post + 614400;

    float* pregates = h1;
    float* dco = h2;

    // zero c_q, c_p, h_q(bf16), h_p(bf16) — contiguous region
    hipMemsetAsync(cq, 0, (size_t)(2 * 2097152) * 4 + (size_t)(2 * 2097152) * 2, stream);

    // weight conversions
    cvtw_k<<<1600, 256, 0, stream>>>(post_Wx, w_pre0, 160, 0, 2, 0, 2);
    cvtw_k<<<1600, 256, 0, stream>>>(post_Wx, w_pre1, 160, 64, 2, 0, 2);
    cvtw_k<<<800, 256, 0, stream>>>(post_Wx, w_post, 160, 128, 1, 0, 3);
    cvtw_k<<<1600, 256, 0, stream>>>(post_Wh, w_post, 64, 0, 2, 1, 3);
    cvtw_k<<<800, 256, 0, stream>>>(prior_Wx, w_prior, 32, 0, 1, 0, 3);
    cvtw_k<<<1600, 256, 0, stream>>>(prior_Wh, w_prior, 64, 0, 2, 1, 3);
    dec1wt_k<<<256, 256, 0, stream>>>(dec1_W, wdec1);

    stem1_k<<<65536, 256, 0, stream>>>(x, stem1_W, stem1_b, h1);
    conv5s2_k<<<dim3(4, 2, 32), 256, 0, stream>>>(h1, stem2_W, stem2_b, h2);
    h2n_k<<<128, 256, 0, stream>>>(h2, h2_n);
    gauss_k<<<4096, 256, 0, stream>>>(h2, gauss_W, gauss_b, eps, zs, z_n, kl_out);

    const size_t GLDS = 216 * GCP * 2;
    // pregates = bias + conv(h2, post_Wx[:, :128]) in two 64-ci halves
    gconv_k<<<dim3(16, 32), 256, GLDS, stream>>>(
        h2_n, 64, 128, (const ushort_t*)nullptr, 0, 0,
        w_pre0, 2, (const float*)nullptr, post_b, pregates);
    gconv_k<<<dim3(16, 32), 256, GLDS, stream>>>(
        h2_n + 64, 64, 128, (const ushort_t*)nullptr, 0, 0,
        w_pre1, 2, pregates, post_b, pregates);

    for (int s = 0; s < KSTEPS - 1; ++s){
        // posterior gates = pregates + conv(z, .) + conv(hq, .)
        gconv_k<<<dim3(16, 32), 256, GLDS, stream>>>(
            z_n, 32, 32, hq_n, 64, 64,
            w_post, 3, pregates, post_b, gates);
        lstm_k<<<8192, 256, 0, stream>>>(gates, cq, hq_n);
        // prior gates = bias + conv(z, .) + conv(hp, .)   (uses z_s before postlin overwrites z_n)
        gconv_k<<<dim3(16, 32), 256, GLDS, stream>>>(
            z_n, 32, 32, hp_n, 64, 64,
            w_prior, 3, (const float*)nullptr, prior_b, gates);
        lstm_k<<<8192, 256, 0, stream>>>(gates, cp, hp_n);
        postlin_k<<<4096, 256, 0, stream>>>(hq_n, postlin_W, postlin_b,
                                            eps + (size_t)(s + 1) * 1048576,
                                            zs + (size_t)(s + 1) * 1048576, z_n, qmu, qs);
        priorlin_k<<<4096, 256, 0, stream>>>(hp_n, priorlin_W, priorlin_b, qmu, qs, kl_out, s + 1);
    }

    for (int k = 0; k < KSTEPS; ++k){
        dec1_k<<<dim3(2, 16, 32), 256, 0, stream>>>(zs + (size_t)k * 1048576, wdec1, dec1_b, h1);
        dec2_k<<<2048, 256, 0, stream>>>(h1, dec2_W, dec2_b, dco + (size_t)k * BATCH * 16384);
    }
    stick_k<<<2048, 256, 0, stream>>>(dco, lm_out);
}

// Round 5
// 3701.094 us; speedup vs baseline: 23.6814x; 1.2675x over previous
//
#include <hip/hip_runtime.h>
#include <math.h>

#define BATCH 32
#define HDIM 128
#define ZDIM 32
#define KSTEPS 6

typedef unsigned short ushort_t;
using bf16x8 = __attribute__((ext_vector_type(8))) short;
using f32x4v = __attribute__((ext_vector_type(4))) float;

__device__ __forceinline__ float softplusf(float x){
    return fmaxf(x, 0.f) + log1pf(expf(-fabsf(x)));
}
__device__ __forceinline__ float sigmoidf(float x){
    return 1.f / (1.f + expf(-x));
}
__device__ __forceinline__ float logsigf(float x){
    return fminf(x, 0.f) - log1pf(expf(-fabsf(x)));
}
__device__ __forceinline__ float bf2f(ushort_t u){
    return __uint_as_float(((unsigned)u) << 16);
}
__device__ __forceinline__ ushort_t f2bf(float f){
    unsigned x = __float_as_uint(f);
    unsigned r = (x + 0x7fffu + ((x >> 16) & 1u)) >> 16;
    return (ushort_t)r;
}

// ---------------- stem1 weight transpose: [co128][75] -> [tap75][co128]
__global__ __launch_bounds__(256) void stem1wt_k(const float* __restrict__ W,
                                                 float* __restrict__ Wo){
    int idx = blockIdx.x * 256 + threadIdx.x;   // 9600
    if (idx >= 9600) return;
    int co = idx & 127, tap = idx >> 7;
    Wo[(tap << 7) + co] = W[co * 75 + tap];
}

// ---------------- stem1: conv 5x5 s2, 3->128, 128x128 -> 64x64, ReLU, out NHWC bf16
// grid (256 px-blocks of 16, 32 n); 256 thr = 2 px * 128 co; 8 px per thread
__global__ __launch_bounds__(256) void stem1_k(const float* __restrict__ x,
                                               const float* __restrict__ WtT, // [tap][co]
                                               const float* __restrict__ bias,
                                               ushort_t* __restrict__ h1n){
    __shared__ float ws[75 * 128];
    const int n = blockIdx.y, pb = blockIdx.x;
    const int co = threadIdx.x & 127, ps = threadIdx.x >> 7;
    for (int i = threadIdx.x; i < 9600; i += 256) ws[i] = WtT[i];
    __syncthreads();
    const float* xb = x + (size_t)n * 3 * 16384;
    float b = bias[co];
    #pragma unroll
    for (int t = 0; t < 8; ++t){
        int pix = (pb << 4) + (t << 1) + ps;
        int oy = pix >> 6, ox = pix & 63;
        float acc = b;
        for (int ci = 0; ci < 3; ++ci){
            #pragma unroll
            for (int ky = 0; ky < 5; ++ky){
                int iy = 2 * oy - 1 + ky;
                if ((unsigned)iy >= 128u) continue;
                const float* xr = xb + (ci << 14) + (iy << 7);
                #pragma unroll
                for (int kx = 0; kx < 5; ++kx){
                    int ix = 2 * ox - 1 + kx;
                    if ((unsigned)ix >= 128u) continue;
                    acc = fmaf(xr[ix], ws[((ci * 25 + ky * 5 + kx) << 7) + co], acc);
                }
            }
        }
        h1n[(((size_t)n << 12) + pix) * 128 + co] = f2bf(fmaxf(acc, 0.f));
    }
}

// ---------------- generic weight convert: OIHW f32 -> [tap][ck][coN][ci32] bf16 (opt. co permute)
__global__ __launch_bounds__(256) void cvtw_k(const float* __restrict__ src,
                                              ushort_t* __restrict__ dst,
                                              int Cfull, int ci_off, int ncs,
                                              int ck_off, int NCHK, int NCO, int permute){
    int idx = blockIdx.x * 256 + threadIdx.x;
    int total = 25 * ncs * NCO * 32;
    if (idx >= total) return;
    int per_tap = ncs * NCO * 32;
    int tap = idx / per_tap;
    int r = idx - tap * per_tap;
    int ckl = r / (NCO * 32);
    int r2 = r - ckl * (NCO * 32);
    int co = r2 >> 5, cl = r2 & 31;
    // slot: s = (ch>>4)*64 + gate*16 + (ch&15), orig co = gate*64 + ch
    int s = permute ? ((((co & 63) >> 4) << 6) | ((co >> 6) << 4) | (co & 15)) : co;
    float v = src[((size_t)co * Cfull + ci_off + (ckl << 5) + cl) * 25 + tap];
    dst[(((size_t)(tap * NCHK + ck_off + ckl)) * NCO + s) * 32 + cl] = f2bf(v);
}

// ---------------- dec1 weight transpose: [co128][ci32][16] -> [ci32][tap16][co128]
__global__ __launch_bounds__(256) void dec1wt_k(const float* __restrict__ W,
                                                float* __restrict__ Wo){
    int idx = blockIdx.x * 256 + threadIdx.x;      // 65536
    int co = idx & 127, tap = (idx >> 7) & 15, ci = idx >> 11;
    Wo[idx] = W[(co << 9) + (ci << 4) + tap];
}

// ---------------- stem2 MFMA: conv 5x5 s2 SAME, 128->128, 64x64 -> 32x32, ReLU
// in: NHWC bf16 [n][4096][128]; out: NHWC f32 + NHWC bf16 [n][1024][128]
// grid (16 row-pairs, 32 n); 4 waves = 2 out-rows x 2 co-halves
#define S2CP 40
__global__ __launch_bounds__(256) void s2m_k(const ushort_t* __restrict__ h1n,
                                             const ushort_t* __restrict__ wb, // [25][4][128][32]
                                             const float* __restrict__ bias,
                                             float* __restrict__ h2f,
                                             ushort_t* __restrict__ h2n){
    __shared__ ushort_t sm[7 * 67 * S2CP];   // 37,520 B
    const int pb = blockIdx.x, n = blockIdx.y;
    const int tid = threadIdx.x, lane = tid & 63, wv = tid >> 6;
    const int ry = wv >> 1, ch_half = wv & 1;
    const int lm = lane & 15, lg = lane >> 4;

    f32x4v z4 = {0.f, 0.f, 0.f, 0.f};
    f32x4v acc[2][4];
    #pragma unroll
    for (int j = 0; j < 2; ++j)
        #pragma unroll
        for (int cf = 0; cf < 4; ++cf) acc[j][cf] = z4;

    for (int ck = 0; ck < 4; ++ck){
        __syncthreads();
        for (int idx = tid; idx < 7 * 67 * 4; idx += 256){
            int ci8 = idx & 3, cell = idx >> 2;
            int r = cell / 67, c = cell - r * 67;
            int iy = (pb << 2) - 1 + r, ix = c - 1;
            bf16x8 v = {0,0,0,0,0,0,0,0};
            if ((unsigned)iy < 64u && (unsigned)ix < 64u)
                v = *(const bf16x8*)(h1n + ((((size_t)n << 12) + (iy << 6) + ix) << 7) + (ck << 5) + (ci8 << 3));
            *(bf16x8*)(sm + cell * S2CP + (ci8 << 3)) = v;
        }
        __syncthreads();
        int ky = 0, kx = 0;
        for (int tap = 0; tap < 25; ++tap){
            bf16x8 a[2];
            #pragma unroll
            for (int j = 0; j < 2; ++j){
                int r = 2 * ry + ky;
                int c = 2 * ((j << 4) + lm) + kx;
                a[j] = *(const bf16x8*)(sm + (r * 67 + c) * S2CP + (lg << 3));
            }
            const ushort_t* wp = wb + ((size_t)(((tap * 4 + ck) << 7) + (ch_half << 6) + lm) << 5) + (lg << 3);
            #pragma unroll
            for (int cf = 0; cf < 4; ++cf){
                bf16x8 b = *(const bf16x8*)(wp + (cf << 9));
                acc[0][cf] = __builtin_amdgcn_mfma_f32_16x16x32_bf16(a[0], b, acc[0][cf], 0, 0, 0);
                acc[1][cf] = __builtin_amdgcn_mfma_f32_16x16x32_bf16(a[1], b, acc[1][cf], 0, 0, 0);
            }
            if (++kx == 5){ kx = 0; ++ky; }
        }
    }
    const int oy = 2 * pb + ry;
    #pragma unroll
    for (int j = 0; j < 2; ++j){
        #pragma unroll
        for (int cf = 0; cf < 4; ++cf){
            int co = (ch_half << 6) + (cf << 4) + lm;
            float b = bias[co];
            #pragma unroll
            for (int reg = 0; reg < 4; ++reg){
                int ox = (j << 4) + (lg << 2) + reg;
                int pix = (oy << 5) + ox;
                float v = fmaxf(acc[j][cf][reg] + b, 0.f);
                size_t o = ((((size_t)n << 10) + pix) << 7) + co;
                h2f[o] = v;
                h2n[o] = f2bf(v);
            }
        }
    }
}

// ---------------- MFMA gate conv: 5x5 SAME over 32x32, 256 out ch (permuted slots), bf16 NHWC in
// plain mode (cst==null): out = (init ? init : bias[orig]) + conv  -> outp (slot layout)
// fused mode (cst!=null): gates -> LSTM update; writes cst (NHWC f32) + hout (NHWC bf16)
#define GCP 104
__global__ __launch_bounds__(256) void gconv_k(
    const ushort_t* __restrict__ in0, int C0, int str0,
    const ushort_t* __restrict__ in1, int C1, int str1,
    const ushort_t* __restrict__ wb, int NCHK,
    const float* __restrict__ initp, const float* __restrict__ bias,
    float* __restrict__ outp,
    float* __restrict__ cst, ushort_t* __restrict__ hout)
{
    extern __shared__ ushort_t sm[];               // [6 rows][36 cols][GCP]
    const int pb = blockIdx.x, n = blockIdx.y;
    const int tid = threadIdx.x, lane = tid & 63, wv = tid >> 6;
    const int Ct = C0 + C1;
    const int nch8 = Ct >> 3;
    for (int idx = tid; idx < 216 * nch8; idx += 256){
        int cell = idx / nch8;
        int c8 = (idx - cell * nch8) << 3;
        int rr = cell / 36, cc = cell - rr * 36;
        int y = pb * 2 - 2 + rr, x = cc - 2;
        bf16x8 v = {0,0,0,0,0,0,0,0};
        if ((unsigned)y < 32u && (unsigned)x < 32u){
            int pix = (y << 5) + x;
            if (c8 < C0) v = *(const bf16x8*)(in0 + ((size_t)((n << 10) + pix)) * str0 + c8);
            else         v = *(const bf16x8*)(in1 + ((size_t)((n << 10) + pix)) * str1 + (c8 - C0));
        }
        *(bf16x8*)(sm + cell * GCP + c8) = v;
    }
    __syncthreads();

    const int wbase = wv << 6;
    const int lm = lane & 15, lg = lane >> 4;
    f32x4v z4 = {0.f, 0.f, 0.f, 0.f};
    f32x4v acc[4][4];
    #pragma unroll
    for (int f = 0; f < 4; ++f)
        #pragma unroll
        for (int cf = 0; cf < 4; ++cf) acc[f][cf] = z4;

    int ky = 0, kx = 0;
    for (int tap = 0; tap < 25; ++tap){
        for (int ck = 0; ck < NCHK; ++ck){
            bf16x8 a[4];
            #pragma unroll
            for (int f = 0; f < 4; ++f){
                int rr = (f >> 1) + ky;
                int cc = ((f & 1) << 4) + lm + kx;
                a[f] = *(const bf16x8*)(sm + (rr * 36 + cc) * GCP + (ck << 5) + (lg << 3));
            }
            const ushort_t* wp = wb + ((size_t)((((tap * NCHK + ck) << 8) + wbase + lm)) << 5) + (lg << 3);
            #pragma unroll
            for (int cf = 0; cf < 4; ++cf){
                bf16x8 b = *(const bf16x8*)(wp + (cf << 9));
                #pragma unroll
                for (int f = 0; f < 4; ++f)
                    acc[f][cf] = __builtin_amdgcn_mfma_f32_16x16x32_bf16(a[f], b, acc[f][cf], 0, 0, 0);
            }
        }
        if (++kx == 5){ kx = 0; ++ky; }
    }

    if (cst == nullptr){
        // plain epilogue: write conv result in SLOT layout
        #pragma unroll
        for (int f = 0; f < 4; ++f){
            int px = (pb << 6) + (f << 4) + (lg << 2);
            #pragma unroll
            for (int cf = 0; cf < 4; ++cf){
                int co = wbase + (cf << 4) + lm;   // slot index
                size_t o = (((size_t)n * 256 + co) << 10) + px;
                f32x4v r = acc[f][cf];
                if (initp){
                    float4 iv = *(const float4*)(initp + o);
                    r[0] += iv.x; r[1] += iv.y; r[2] += iv.z; r[3] += iv.w;
                } else {
                    int orig = (((co >> 4) & 3) << 6) | ((co >> 6) << 4) | (co & 15);
                    float b = bias[orig];
                    r[0] += b; r[1] += b; r[2] += b; r[3] += b;
                }
                float4 st = {r[0], r[1], r[2], r[3]};
                *(float4*)(outp + o) = st;
            }
        }
    } else {
        // fused LSTM epilogue: cf = gate (i,f,g,o), channel = wv*16+lm
        const int ch = (wv << 4) + lm;
        #pragma unroll
        for (int f = 0; f < 4; ++f){
            int pxb = (pb << 6) + (f << 4) + (lg << 2);
            f32x4v g4[4];
            #pragma unroll
            for (int cf = 0; cf < 4; ++cf){
                int slot = wbase + (cf << 4) + lm;
                if (initp){
                    g4[cf] = *(const f32x4v*)(initp + (((size_t)n * 256 + slot) << 10) + pxb);
                } else {
                    float b = bias[(cf << 6) + ch];
                    f32x4v bb = {b, b, b, b};
                    g4[cf] = bb;
                }
            }
            #pragma unroll
            for (int reg = 0; reg < 4; ++reg){
                float ig = acc[f][0][reg] + g4[0][reg];
                float fg = acc[f][1][reg] + g4[1][reg];
                float gg = acc[f][2][reg] + g4[2][reg];
                float og = acc[f][3][reg] + g4[3][reg];
                int px = pxb + reg;
                size_t o = ((((size_t)n << 10) + px) << 6) + ch;
                float cv = cst[o];
                float c2 = sigmoidf(fg) * cv + sigmoidf(ig) * tanhf(gg);
                cst[o] = c2;
                hout[o] = f2bf(sigmoidf(og) * tanhf(c2));
            }
        }
    }
}

// ---------------- gauss head: 1x1 conv 128->64 on NHWC f32 h2; z (f32 NCHW + NHWC bf16), KL
__global__ __launch_bounds__(256) void gauss_k(const float* __restrict__ h,
                                               const float* __restrict__ Wg,
                                               const float* __restrict__ bg,
                                               const float* __restrict__ eps0,
                                               float* __restrict__ z0,
                                               ushort_t* __restrict__ zn,
                                               float* __restrict__ kl_out){
    __shared__ float w[64 * 128];
    int flat = blockIdx.x * 256 + threadIdx.x;     // [n][zc][pix]
    int pix = flat & 1023, zc = (flat >> 10) & 31, n = flat >> 15;
    for (int i = threadIdx.x; i < 64 * 128; i += 256) w[i] = Wg[i];
    __syncthreads();
    const float* hb = h + ((((size_t)n << 10) + pix) << 7);
    float amu = bg[zc], alv = bg[zc + 32];
    for (int ci = 0; ci < HDIM; ++ci){
        float hv = hb[ci];
        amu += hv * w[zc * 128 + ci];
        alv += hv * w[(zc + 32) * 128 + ci];
    }
    float s = softplusf(alv + 0.5f) + 1e-8f;
    float z = amu + s * eps0[flat];
    z0[flat] = z;
    zn[((((size_t)n << 10) + pix) << 5) + zc] = f2bf(z);
    float kl = -logf(s) + 0.5f * (s * s + amu * amu) - 0.5f;
    kl_out[(size_t)flat * KSTEPS + 0] = kl;
}

// ---------------- postlin: 1x1 conv 64->64 on NHWC bf16 h_q; z = mu + s*eps
__global__ __launch_bounds__(256) void postlin_k(const ushort_t* __restrict__ hq,
                                                 const float* __restrict__ Wl,
                                                 const float* __restrict__ bl,
                                                 const float* __restrict__ eps_s,
                                                 float* __restrict__ z_out,
                                                 ushort_t* __restrict__ zn,
                                                 float* __restrict__ qmu, float* __restrict__ qs){
    __shared__ float w[64 * 64];
    int flat = blockIdx.x * 256 + threadIdx.x;
    int pix = flat & 1023, zc = (flat >> 10) & 31, n = flat >> 15;
    for (int i = threadIdx.x; i < 64 * 64; i += 256) w[i] = Wl[i];
    __syncthreads();
    const ushort_t* hb = hq + ((((size_t)n << 10) + pix) << 6);
    float amu = bl[zc], alv = bl[zc + 32];
    for (int ci = 0; ci < 64; ++ci){
        float hv = bf2f(hb[ci]);
        amu += hv * w[zc * 64 + ci];
        alv += hv * w[(zc + 32) * 64 + ci];
    }
    float s = softplusf(alv + 0.5f) + 1e-8f;
    float z = amu + s * eps_s[flat];
    z_out[flat] = z;
    zn[((((size_t)n << 10) + pix) << 5) + zc] = f2bf(z);
    qmu[flat] = amu;
    qs[flat] = s;
}

// ---------------- priorlin + KL (NHWC bf16 h_p)
__global__ __launch_bounds__(256) void priorlin_k(const ushort_t* __restrict__ hp,
                                                  const float* __restrict__ Wl,
                                                  const float* __restrict__ bl,
                                                  const float* __restrict__ qmu,
                                                  const float* __restrict__ qs,
                                                  float* __restrict__ kl_out, int step){
    __shared__ float w[64 * 64];
    int flat = blockIdx.x * 256 + threadIdx.x;
    int pix = flat & 1023, zc = (flat >> 10) & 31, n = flat >> 15;
    for (int i = threadIdx.x; i < 64 * 64; i += 256) w[i] = Wl[i];
    __syncthreads();
    const ushort_t* hb = hp + ((((size_t)n << 10) + pix) << 6);
    float amu = bl[zc], alv = bl[zc + 32];
    for (int ci = 0; ci < 64; ++ci){
        float hv = bf2f(hb[ci]);
        amu += hv * w[zc * 64 + ci];
        alv += hv * w[(zc + 32) * 64 + ci];
    }
    float ps = softplusf(alv + 0.5f) + 1e-8f;
    float qm = qmu[flat], q = qs[flat];
    float d = qm - amu;
    float kl = logf(ps / q) + (q * q + d * d) / (2.f * ps * ps) - 0.5f;
    kl_out[(size_t)flat * KSTEPS + step] = kl;
}

// ---------------- dec1 tiled: conv_transpose 4x4 s2 SAME, 32->128, 32x32 -> 64x64, ReLU
__global__ __launch_bounds__(256) void dec1_k(const float* __restrict__ z,
                                              const float* __restrict__ Wt,  // [ci32][tap16][co128]
                                              const float* __restrict__ bias,
                                              float* __restrict__ out){
    __shared__ float zin[32][10][13];
    __shared__ float ws[4][16][64];
    const int cob = blockIdx.x << 6;
    const int ty = blockIdx.y >> 2, tx = blockIdx.y & 3;
    const int n = blockIdx.z;
    const int tid = threadIdx.x;
    const int cg = tid >> 5, pg = tid & 31;
    const int oyl = pg >> 1, xh = pg & 1;
    const int oy = (ty << 4) + oyl;
    const int oxb = (tx << 4) + (xh << 3);

    for (int idx = tid; idx < 3200; idx += 256){
        int ci = idx / 100, r = idx - ci * 100;
        int ry = r / 10, rx = r - ry * 10;
        int iy = (ty << 3) - 1 + ry, ix = (tx << 3) - 1 + rx;
        float v = 0.f;
        if ((unsigned)iy < 32u && (unsigned)ix < 32u)
            v = z[(((size_t)n * 32 + ci) << 10) + (iy << 5) + ix];
        zin[ci][ry][rx] = v;
    }

    float acc[8][8];
    #pragma unroll
    for (int c = 0; c < 8; ++c)
        #pragma unroll
        for (int p = 0; p < 8; ++p) acc[c][p] = 0.f;

    const int py = oy & 1;
    const int ryA = (oyl >> 1) + py;
    const int kyA = py, kyB = py + 2;
    const int xq = xh << 2;

    for (int cb = 0; cb < 32; cb += 4){
        __syncthreads();
        for (int idx = tid; idx < 4096; idx += 256){
            int cl = idx >> 10, r = idx & 1023;
            int tap = r >> 6, co = r & 63;
            ws[cl][tap][co] = Wt[((size_t)(cb + cl) << 11) + (tap << 7) + cob + co];
        }
        __syncthreads();
        #pragma unroll
        for (int cl = 0; cl < 4; ++cl){
            float rvA[6], rvB[6];
            #pragma unroll
            for (int i = 0; i < 6; ++i){
                rvA[i] = zin[cb + cl][ryA][xq + i];
                rvB[i] = zin[cb + cl][ryA + 1][xq + i];
            }
            #pragma unroll
            for (int t = 0; t < 2; ++t){
                const float* rv = t ? rvB : rvA;
                int kyt = t ? kyB : kyA;
                #pragma unroll
                for (int kx = 0; kx < 4; ++kx){
                    int pxp = kx & 1, d = kx >> 1;
                    const float4* q = (const float4*)&ws[cl][(kyt << 2) + kx][cg << 3];
                    float4 w0 = q[0], w1 = q[1];
                    float w8[8] = {w0.x, w0.y, w0.z, w0.w, w1.x, w1.y, w1.z, w1.w};
                    #pragma unroll
                    for (int ph = 0; ph < 4; ++ph){
                        int p = ph * 2 + pxp;
                        float inv = rv[ph + pxp + d];
                        #pragma unroll
                        for (int c = 0; c < 8; ++c)
                            acc[c][p] = fmaf(inv, w8[c], acc[c][p]);
                    }
                }
            }
        }
    }

    #pragma unroll
    for (int c = 0; c < 8; ++c){
        float b = bias[cob + (cg << 3) + c];
        size_t o = (((size_t)n * 128 + cob + (cg << 3) + c) << 12) + (oy << 6) + oxb;
        float4 o0 = {fmaxf(acc[c][0] + b, 0.f), fmaxf(acc[c][1] + b, 0.f),
                     fmaxf(acc[c][2] + b, 0.f), fmaxf(acc[c][3] + b, 0.f)};
        float4 o1 = {fmaxf(acc[c][4] + b, 0.f), fmaxf(acc[c][5] + b, 0.f),
                     fmaxf(acc[c][6] + b, 0.f), fmaxf(acc[c][7] + b, 0.f)};
        *reinterpret_cast<float4*>(out + o) = o0;
        *reinterpret_cast<float4*>(out + o + 4) = o1;
    }
}

// ---------------- dec2: conv_transpose 4x4 s2 SAME, 128->1, 64x64 -> 128x128
__global__ __launch_bounds__(256) void dec2_k(const float* __restrict__ a,
                                              const float* __restrict__ Wt,
                                              const float* __restrict__ bias,
                                              float* __restrict__ out){
    __shared__ float w[HDIM * 16];
    int flat = blockIdx.x * 256 + threadIdx.x;     // [n][oy][ox]
    int ox = flat & 127, oy = (flat >> 7) & 127, n = flat >> 14;
    for (int i = threadIdx.x; i < HDIM * 16; i += 256) w[i] = Wt[i];
    __syncthreads();
    float acc = bias[0];
    const float* ab = a + (size_t)n * HDIM * 4096;
    #pragma unroll
    for (int ky = 0; ky < 4; ++ky){
        int t = oy - 2 + ky;
        if (t & 1) continue;
        int iy = t >> 1;
        if ((unsigned)iy >= 64u) continue;
        #pragma unroll
        for (int kx = 0; kx < 4; ++kx){
            int tx = ox - 2 + kx;
            if (tx & 1) continue;
            int ix = tx >> 1;
            if ((unsigned)ix >= 64u) continue;
            const float* ap = ab + (iy << 6) + ix;
            const float* wp = w + ky * 4 + kx;
            for (int ci = 0; ci < HDIM; ++ci){
                acc += ap[(size_t)ci << 12] * wp[ci * 16];
            }
        }
    }
    out[flat] = acc;
}

// ---------------- stick-breaking over K decoder outputs
__global__ __launch_bounds__(256) void stick_k(const float* __restrict__ dec,
                                               float* __restrict__ lm){
    int flat = blockIdx.x * 256 + threadIdx.x;
    float ss = 0.f;
    #pragma unroll
    for (int k = 0; k < KSTEPS; ++k){
        float v = dec[(size_t)k * (BATCH * 16384) + flat];
        if (k < KSTEPS - 1){
            lm[(size_t)k * (BATCH * 16384) + flat] = ss + logsigf(v);
            ss += logsigf(-v);
        } else {
            lm[(size_t)k * (BATCH * 16384) + flat] = ss + logsigf(v);
        }
    }
}

extern "C" void kernel_launch(void* const* d_in, const int* in_sizes, int n_in,
                              void* d_out, int out_size, void* d_ws, size_t ws_size,
                              hipStream_t stream){
    const float* x        = (const float*)d_in[0];
    const float* eps      = (const float*)d_in[1];
    const float* stem1_W  = (const float*)d_in[2];
    const float* stem1_b  = (const float*)d_in[3];
    const float* stem2_W  = (const float*)d_in[4];
    const float* stem2_b  = (const float*)d_in[5];
    const float* gauss_W  = (const float*)d_in[6];
    const float* gauss_b  = (const float*)d_in[7];
    const float* post_Wx  = (const float*)d_in[8];
    const float* post_Wh  = (const float*)d_in[9];
    const float* post_b   = (const float*)d_in[10];
    const float* postlin_W= (const float*)d_in[11];
    const float* postlin_b= (const float*)d_in[12];
    const float* prior_Wx = (const float*)d_in[13];
    const float* prior_Wh = (const float*)d_in[14];
    const float* prior_b  = (const float*)d_in[15];
    const float* priorlin_W=(const float*)d_in[16];
    const float* priorlin_b=(const float*)d_in[17];
    const float* dec1_W   = (const float*)d_in[18];
    const float* dec1_b   = (const float*)d_in[19];
    const float* dec2_W   = (const float*)d_in[20];
    const float* dec2_b   = (const float*)d_in[21];

    float* lm_out = (float*)d_out;
    float* kl_out = lm_out + (size_t)KSTEPS * BATCH * 16384;

    float* p = (float*)d_ws;
    float* h1    = p; p += (size_t)BATCH * HDIM * 64 * 64;       // 16.78M f: h1n alias / pregates alias / dec1 out
    float* h2f   = p; p += (size_t)BATCH * HDIM * 32 * 32;       // 4.19M f NHWC (dco alias)
    float* zs    = p; p += (size_t)KSTEPS * BATCH * ZDIM * 1024; // 6.29M f
    float* cq    = p; p += (size_t)BATCH * 64 * 1024;            // NHWC f32 (zeroed)
    float* cp    = p; p += (size_t)BATCH * 64 * 1024;
    ushort_t* hq_a = (ushort_t*)p; p += (size_t)BATCH * 64 * 1024 / 2;   // bf16 NHWC (zeroed)
    ushort_t* hp_a = (ushort_t*)p; p += (size_t)BATCH * 64 * 1024 / 2;   // (zeroed)
    ushort_t* hq_b = (ushort_t*)p; p += (size_t)BATCH * 64 * 1024 / 2;
    ushort_t* hp_b = (ushort_t*)p; p += (size_t)BATCH * 64 * 1024 / 2;
    float* qmu   = p; p += (size_t)BATCH * ZDIM * 1024;
    float* qs    = p; p += (size_t)BATCH * ZDIM * 1024;
    ushort_t* z_n  = (ushort_t*)p; p += (size_t)BATCH * ZDIM * 1024 / 2; // bf16 NHWC [n][pix][32]
    ushort_t* h2_n = (ushort_t*)p; p += (size_t)BATCH * HDIM * 1024 / 2; // bf16 NHWC [n][pix][128]
    ushort_t* wbuf = (ushort_t*)p; p += 1433600;                         // 2,867,200 ushorts
    float* wdec1 = p; p += 65536;
    float* wstem1 = p; p += 9600;

    ushort_t* w_pre0  = wbuf;                   // 25*2*256*32 = 409600
    ushort_t* w_pre1  = w_pre0 + 409600;
    ushort_t* w_post  = w_pre1 + 409600;        // 25*3*256*32 = 614400
    ushort_t* w_prior = w_post + 614400;
    ushort_t* w_stem2 = w_prior + 614400;       // 25*4*128*32 = 409600

    ushort_t* h1n = (ushort_t*)h1;   // stem1 out; dead before pregates/dec1 reuse h1
    float* pregates = h1;
    float* dco = h2f;

    // zero c_q, c_p (f32) + h_q, h_p "a" buffers (bf16) — contiguous
    hipMemsetAsync(cq, 0, (size_t)(2 * 2097152) * 4 + (size_t)(2 * 2097152) * 2, stream);

    // weight conversions
    cvtw_k<<<1600, 256, 0, stream>>>(post_Wx, w_pre0, 160, 0, 2, 0, 2, 256, 1);
    cvtw_k<<<1600, 256, 0, stream>>>(post_Wx, w_pre1, 160, 64, 2, 0, 2, 256, 1);
    cvtw_k<<<800, 256, 0, stream>>>(post_Wx, w_post, 160, 128, 1, 0, 3, 256, 1);
    cvtw_k<<<1600, 256, 0, stream>>>(post_Wh, w_post, 64, 0, 2, 1, 3, 256, 1);
    cvtw_k<<<800, 256, 0, stream>>>(prior_Wx, w_prior, 32, 0, 1, 0, 3, 256, 1);
    cvtw_k<<<1600, 256, 0, stream>>>(prior_Wh, w_prior, 64, 0, 2, 1, 3, 256, 1);
    cvtw_k<<<1600, 256, 0, stream>>>(stem2_W, w_stem2, 128, 0, 4, 0, 4, 128, 0);
    dec1wt_k<<<256, 256, 0, stream>>>(dec1_W, wdec1);
    stem1wt_k<<<38, 256, 0, stream>>>(stem1_W, wstem1);

    stem1_k<<<dim3(256, 32), 256, 0, stream>>>(x, wstem1, stem1_b, h1n);
    s2m_k<<<dim3(16, 32), 256, 0, stream>>>(h1n, w_stem2, stem2_b, h2f, h2_n);
    gauss_k<<<4096, 256, 0, stream>>>(h2f, gauss_W, gauss_b, eps, zs, z_n, kl_out);

    const size_t GLDS = 216 * GCP * 2;
    // pregates = bias + conv(h2, post_Wx[:, :128]) in two 64-ci halves (slot layout)
    gconv_k<<<dim3(16, 32), 256, GLDS, stream>>>(
        h2_n, 64, 128, (const ushort_t*)nullptr, 0, 0,
        w_pre0, 2, (const float*)nullptr, post_b, pregates,
        (float*)nullptr, (ushort_t*)nullptr);
    gconv_k<<<dim3(16, 32), 256, GLDS, stream>>>(
        h2_n + 64, 64, 128, (const ushort_t*)nullptr, 0, 0,
        w_pre1, 2, pregates, post_b, pregates,
        (float*)nullptr, (ushort_t*)nullptr);

    ushort_t* hq_in = hq_a; ushort_t* hq_out = hq_b;
    ushort_t* hp_in = hp_a; ushort_t* hp_out = hp_b;
    for (int s = 0; s < KSTEPS - 1; ++s){
        // posterior: gates = pregates + conv(z) + conv(hq) -> fused LSTM -> cq, hq_out
        gconv_k<<<dim3(16, 32), 256, GLDS, stream>>>(
            z_n, 32, 32, hq_in, 64, 64,
            w_post, 3, pregates, post_b, (float*)nullptr,
            cq, hq_out);
        // prior: gates = bias + conv(z) + conv(hp) -> fused LSTM -> cp, hp_out
        gconv_k<<<dim3(16, 32), 256, GLDS, stream>>>(
            z_n, 32, 32, hp_in, 64, 64,
            w_prior, 3, (const float*)nullptr, prior_b, (float*)nullptr,
            cp, hp_out);
        postlin_k<<<4096, 256, 0, stream>>>(hq_out, postlin_W, postlin_b,
                                            eps + (size_t)(s + 1) * 1048576,
                                            zs + (size_t)(s + 1) * 1048576, z_n, qmu, qs);
        priorlin_k<<<4096, 256, 0, stream>>>(hp_out, priorlin_W, priorlin_b, qmu, qs, kl_out, s + 1);
        ushort_t* t;
        t = hq_in; hq_in = hq_out; hq_out = t;
        t = hp_in; hp_in = hp_out; hp_out = t;
    }

    for (int k = 0; k < KSTEPS; ++k){
        dec1_k<<<dim3(2, 16, 32), 256, 0, stream>>>(zs + (size_t)k * 1048576, wdec1, dec1_b, h1);
        dec2_k<<<2048, 256, 0, stream>>>(h1, dec2_W, dec2_b, dco + (size_t)k * BATCH * 16384);
    }
    stick_k<<<2048, 256, 0, stream>>>(dco, lm_out);
}

// Round 6
// 2285.036 us; speedup vs baseline: 38.3570x; 1.6197x over previous
//
#include <hip/hip_runtime.h>
#include <math.h>

#define BATCH 32
#define HDIM 128
#define ZDIM 32
#define KSTEPS 6

typedef unsigned short ushort_t;
using bf16x8 = __attribute__((ext_vector_type(8))) short;
using f32x4v = __attribute__((ext_vector_type(4))) float;

__device__ __forceinline__ float softplusf(float x){
    return fmaxf(x, 0.f) + log1pf(expf(-fabsf(x)));
}
__device__ __forceinline__ float sigmoidf(float x){
    return 1.f / (1.f + expf(-x));
}
__device__ __forceinline__ float logsigf(float x){
    return fminf(x, 0.f) - log1pf(expf(-fabsf(x)));
}
__device__ __forceinline__ float bf2f(ushort_t u){
    return __uint_as_float(((unsigned)u) << 16);
}
__device__ __forceinline__ ushort_t f2bf(float f){
    unsigned x = __float_as_uint(f);
    unsigned r = (x + 0x7fffu + ((x >> 16) & 1u)) >> 16;
    return (ushort_t)r;
}

// ---------------- weight prep kernels ----------------
__global__ __launch_bounds__(256) void stem1wt_k(const float* __restrict__ W,
                                                 float* __restrict__ Wo){
    int idx = blockIdx.x * 256 + threadIdx.x;   // 9600
    if (idx >= 9600) return;
    int co = idx & 127, tap = idx >> 7;
    Wo[(tap << 7) + co] = W[co * 75 + tap];
}

// OIHW f32 -> [tap][ck][coN][ci32] bf16 (opt. gate-slot permute on co)
__global__ __launch_bounds__(256) void cvtw_k(const float* __restrict__ src,
                                              ushort_t* __restrict__ dst,
                                              int Cfull, int ci_off, int ncs,
                                              int ck_off, int NCHK, int NCO, int permute){
    int idx = blockIdx.x * 256 + threadIdx.x;
    int total = 25 * ncs * NCO * 32;
    if (idx >= total) return;
    int per_tap = ncs * NCO * 32;
    int tap = idx / per_tap;
    int r = idx - tap * per_tap;
    int ckl = r / (NCO * 32);
    int r2 = r - ckl * (NCO * 32);
    int co = r2 >> 5, cl = r2 & 31;
    int s = permute ? ((((co & 63) >> 4) << 6) | ((co >> 6) << 4) | (co & 15)) : co;
    float v = src[((size_t)co * Cfull + ci_off + (ckl << 5) + cl) * 25 + tap];
    dst[(((size_t)(tap * NCHK + ck_off + ckl)) * NCO + s) * 32 + cl] = f2bf(v);
}

// dec1_W [co128][ci32][tap16] f32 -> [tap16][co128][ci32] bf16
__global__ __launch_bounds__(256) void dec1wb_k(const float* __restrict__ W,
                                                ushort_t* __restrict__ Wo){
    int idx = blockIdx.x * 256 + threadIdx.x;      // 65536
    int ci = idx & 31, co = (idx >> 5) & 127, tap = idx >> 12;
    Wo[idx] = f2bf(W[(((co << 5) + ci) << 4) + tap]);
}

// dec2_W [ci128][tap16] f32 -> [tap16][ci128] f32
__global__ __launch_bounds__(256) void dec2wt_k(const float* __restrict__ W,
                                                float* __restrict__ Wo){
    int idx = blockIdx.x * 256 + threadIdx.x;      // 2048
    if (idx >= 2048) return;
    int ci = idx & 127, tap = idx >> 7;
    Wo[idx] = W[(ci << 4) + tap];
}

// ---------------- stem1: conv 5x5 s2, 3->128, 128x128 -> 64x64, ReLU, out NHWC bf16
// grid (256 pb, 32 n): pb -> oy = pb>>2, oxb = (pb&3)*16. LDS-staged input tile.
__global__ __launch_bounds__(256) void stem1_k(const float* __restrict__ x,
                                               const float* __restrict__ WtT, // [tap75][co128]
                                               const float* __restrict__ bias,
                                               ushort_t* __restrict__ h1n){
    __shared__ float ws[75 * 128];
    __shared__ float xs[3][5][36];
    const int n = blockIdx.y, pb = blockIdx.x;
    const int oy = pb >> 2, oxb = (pb & 3) << 4;
    const int tid = threadIdx.x;
    const int co = tid & 127, ps = tid >> 7;
    for (int i = tid; i < 9600; i += 256) ws[i] = WtT[i];
    for (int idx = tid; idx < 525; idx += 256){
        int ci = idx / 175, r = (idx - ci * 175) / 35, c = idx - ci * 175 - r * 35;
        int iy = 2 * oy - 1 + r, ix = 2 * oxb - 1 + c;
        float v = 0.f;
        if ((unsigned)iy < 128u && (unsigned)ix < 128u)
            v = x[(size_t)n * 49152 + (ci << 14) + (iy << 7) + ix];
        xs[ci][r][c] = v;
    }
    __syncthreads();
    float b = bias[co];
    float acc[8];
    #pragma unroll
    for (int t = 0; t < 8; ++t) acc[t] = b;
    #pragma unroll
    for (int ci = 0; ci < 3; ++ci){
        #pragma unroll
        for (int ky = 0; ky < 5; ++ky){
            const float* row = &xs[ci][ky][0];
            #pragma unroll
            for (int kx = 0; kx < 5; ++kx){
                float wv = ws[((ci * 25 + ky * 5 + kx) << 7) + co];
                #pragma unroll
                for (int t = 0; t < 8; ++t)
                    acc[t] = fmaf(row[4 * t + 2 * ps + kx], wv, acc[t]);
            }
        }
    }
    #pragma unroll
    for (int t = 0; t < 8; ++t){
        int pix = (oy << 6) + oxb + (t << 1) + ps;
        h1n[((((size_t)n << 12) + pix) << 7) + co] = f2bf(fmaxf(acc[t], 0.f));
    }
}

// ---------------- stem2 MFMA: conv 5x5 s2 SAME, 128->128, 64x64 -> 32x32, ReLU
#define S2CP 40
__global__ __launch_bounds__(256) void s2m_k(const ushort_t* __restrict__ h1n,
                                             const ushort_t* __restrict__ wb, // [25][4][128][32]
                                             const float* __restrict__ bias,
                                             float* __restrict__ h2f,
                                             ushort_t* __restrict__ h2n){
    __shared__ ushort_t sm[7 * 67 * S2CP];
    const int pb = blockIdx.x, n = blockIdx.y;
    const int tid = threadIdx.x, lane = tid & 63, wv = tid >> 6;
    const int ry = wv >> 1, ch_half = wv & 1;
    const int lm = lane & 15, lg = lane >> 4;

    f32x4v z4 = {0.f, 0.f, 0.f, 0.f};
    f32x4v acc[2][4];
    #pragma unroll
    for (int j = 0; j < 2; ++j)
        #pragma unroll
        for (int cf = 0; cf < 4; ++cf) acc[j][cf] = z4;

    for (int ck = 0; ck < 4; ++ck){
        __syncthreads();
        for (int idx = tid; idx < 7 * 67 * 4; idx += 256){
            int ci8 = idx & 3, cell = idx >> 2;
            int r = cell / 67, c = cell - r * 67;
            int iy = (pb << 2) - 1 + r, ix = c - 1;
            bf16x8 v = {0,0,0,0,0,0,0,0};
            if ((unsigned)iy < 64u && (unsigned)ix < 64u)
                v = *(const bf16x8*)(h1n + ((((size_t)n << 12) + (iy << 6) + ix) << 7) + (ck << 5) + (ci8 << 3));
            *(bf16x8*)(sm + cell * S2CP + (ci8 << 3)) = v;
        }
        __syncthreads();
        int ky = 0, kx = 0;
        for (int tap = 0; tap < 25; ++tap){
            bf16x8 a[2];
            #pragma unroll
            for (int j = 0; j < 2; ++j){
                int r = 2 * ry + ky;
                int c = 2 * ((j << 4) + lm) + kx;
                a[j] = *(const bf16x8*)(sm + (r * 67 + c) * S2CP + (lg << 3));
            }
            const ushort_t* wp = wb + ((size_t)(((tap * 4 + ck) << 7) + (ch_half << 6) + lm) << 5) + (lg << 3);
            #pragma unroll
            for (int cf = 0; cf < 4; ++cf){
                bf16x8 b = *(const bf16x8*)(wp + (cf << 9));
                acc[0][cf] = __builtin_amdgcn_mfma_f32_16x16x32_bf16(a[0], b, acc[0][cf], 0, 0, 0);
                acc[1][cf] = __builtin_amdgcn_mfma_f32_16x16x32_bf16(a[1], b, acc[1][cf], 0, 0, 0);
            }
            if (++kx == 5){ kx = 0; ++ky; }
        }
    }
    const int oy = 2 * pb + ry;
    #pragma unroll
    for (int j = 0; j < 2; ++j){
        #pragma unroll
        for (int cf = 0; cf < 4; ++cf){
            int co = (ch_half << 6) + (cf << 4) + lm;
            float b = bias[co];
            #pragma unroll
            for (int reg = 0; reg < 4; ++reg){
                int ox = (j << 4) + (lg << 2) + reg;
                int pix = (oy << 5) + ox;
                float v = fmaxf(acc[j][cf][reg] + b, 0.f);
                size_t o = ((((size_t)n << 10) + pix) << 7) + co;
                h2f[o] = v;
                h2n[o] = f2bf(v);
            }
        }
    }
}

// ---------------- pregates: 5x5 SAME conv of h2 (128 ci), 256 slots out, bias-init
#define GCP2 136
__global__ __launch_bounds__(256) void pregates_k(
    const ushort_t* __restrict__ in0,
    const ushort_t* __restrict__ wb,      // [25][4][256][32]
    const float* __restrict__ bias,
    float* __restrict__ outp)
{
    __shared__ ushort_t sm[216 * GCP2];
    const int pb = blockIdx.x, n = blockIdx.y;
    const int tid = threadIdx.x, lane = tid & 63, wv = tid >> 6;
    for (int idx = tid; idx < 216 * 16; idx += 256){
        int cell = idx >> 4;
        int c8 = (idx & 15) << 3;
        int rr = cell / 36, cc = cell - rr * 36;
        int y = pb * 2 - 2 + rr, x = cc - 2;
        bf16x8 v = {0,0,0,0,0,0,0,0};
        if ((unsigned)y < 32u && (unsigned)x < 32u){
            int pix = (y << 5) + x;
            v = *(const bf16x8*)(in0 + (((size_t)((n << 10) + pix)) << 7) + c8);
        }
        *(bf16x8*)(sm + cell * GCP2 + c8) = v;
    }
    __syncthreads();

    const int wbase = wv << 6;
    const int lm = lane & 15, lg = lane >> 4;
    f32x4v z4 = {0.f, 0.f, 0.f, 0.f};
    f32x4v acc[4][4];
    #pragma unroll
    for (int f = 0; f < 4; ++f)
        #pragma unroll
        for (int cf = 0; cf < 4; ++cf) acc[f][cf] = z4;

    int ky = 0, kx = 0;
    for (int tap = 0; tap < 25; ++tap){
        for (int ck = 0; ck < 4; ++ck){
            bf16x8 a[4];
            #pragma unroll
            for (int f = 0; f < 4; ++f){
                int rr = (f >> 1) + ky;
                int cc = ((f & 1) << 4) + lm + kx;
                a[f] = *(const bf16x8*)(sm + (rr * 36 + cc) * GCP2 + (ck << 5) + (lg << 3));
            }
            const ushort_t* wp = wb + ((size_t)((((tap * 4 + ck) << 8) + wbase + lm)) << 5) + (lg << 3);
            #pragma unroll
            for (int cf = 0; cf < 4; ++cf){
                bf16x8 b = *(const bf16x8*)(wp + (cf << 9));
                #pragma unroll
                for (int f = 0; f < 4; ++f)
                    acc[f][cf] = __builtin_amdgcn_mfma_f32_16x16x32_bf16(a[f], b, acc[f][cf], 0, 0, 0);
            }
        }
        if (++kx == 5){ kx = 0; ++ky; }
    }

    #pragma unroll
    for (int f = 0; f < 4; ++f){
        int px = (pb << 6) + (f << 4) + (lg << 2);
        #pragma unroll
        for (int cf = 0; cf < 4; ++cf){
            int co = wbase + (cf << 4) + lm;   // slot
            int orig = (((co >> 4) & 3) << 6) | ((co >> 6) << 4) | (co & 15);
            float b = bias[orig];
            size_t o = (((size_t)n * 256 + co) << 10) + px;
            float4 st = {acc[f][cf][0] + b, acc[f][cf][1] + b, acc[f][cf][2] + b, acc[f][cf][3] + b};
            *(float4*)(outp + o) = st;
        }
    }
}

// ---------------- merged posterior+prior gate conv + fused LSTM (grid.z: 0=post, 1=prior)
#define GCP 104
__global__ __launch_bounds__(256) void qp_gconv_k(
    const ushort_t* __restrict__ zn,
    const ushort_t* __restrict__ hq_in, const ushort_t* __restrict__ hp_in,
    const ushort_t* __restrict__ w_post, const ushort_t* __restrict__ w_prior,
    const float* __restrict__ pregates,
    const float* __restrict__ post_b, const float* __restrict__ prior_b,
    float* __restrict__ cq, float* __restrict__ cp,
    ushort_t* __restrict__ hq_out, ushort_t* __restrict__ hp_out)
{
    __shared__ ushort_t sm[216 * GCP];
    const int pb = blockIdx.x, n = blockIdx.y, pr = blockIdx.z;
    const ushort_t* in1 = pr ? hp_in : hq_in;
    const ushort_t* wb  = pr ? w_prior : w_post;
    const float* initp  = pr ? (const float*)nullptr : pregates;
    const float* bias   = pr ? prior_b : post_b;
    float* cst          = pr ? cp : cq;
    ushort_t* hout      = pr ? hp_out : hq_out;

    const int tid = threadIdx.x, lane = tid & 63, wv = tid >> 6;
    for (int idx = tid; idx < 216 * 12; idx += 256){
        int cell = idx / 12;
        int c8 = (idx - cell * 12) << 3;
        int rr = cell / 36, cc = cell - rr * 36;
        int y = pb * 2 - 2 + rr, x = cc - 2;
        bf16x8 v = {0,0,0,0,0,0,0,0};
        if ((unsigned)y < 32u && (unsigned)x < 32u){
            int pix = (y << 5) + x;
            if (c8 < 32) v = *(const bf16x8*)(zn + (((size_t)((n << 10) + pix)) << 5) + c8);
            else         v = *(const bf16x8*)(in1 + (((size_t)((n << 10) + pix)) << 6) + (c8 - 32));
        }
        *(bf16x8*)(sm + cell * GCP + c8) = v;
    }
    __syncthreads();

    const int wbase = wv << 6;
    const int lm = lane & 15, lg = lane >> 4;
    f32x4v z4 = {0.f, 0.f, 0.f, 0.f};
    f32x4v acc[4][4];
    #pragma unroll
    for (int f = 0; f < 4; ++f)
        #pragma unroll
        for (int cf = 0; cf < 4; ++cf) acc[f][cf] = z4;

    int ky = 0, kx = 0;
    for (int tap = 0; tap < 25; ++tap){
        for (int ck = 0; ck < 3; ++ck){
            bf16x8 a[4];
            #pragma unroll
            for (int f = 0; f < 4; ++f){
                int rr = (f >> 1) + ky;
                int cc = ((f & 1) << 4) + lm + kx;
                a[f] = *(const bf16x8*)(sm + (rr * 36 + cc) * GCP + (ck << 5) + (lg << 3));
            }
            const ushort_t* wp = wb + ((size_t)((((tap * 3 + ck) << 8) + wbase + lm)) << 5) + (lg << 3);
            #pragma unroll
            for (int cf = 0; cf < 4; ++cf){
                bf16x8 b = *(const bf16x8*)(wp + (cf << 9));
                #pragma unroll
                for (int f = 0; f < 4; ++f)
                    acc[f][cf] = __builtin_amdgcn_mfma_f32_16x16x32_bf16(a[f], b, acc[f][cf], 0, 0, 0);
            }
        }
        if (++kx == 5){ kx = 0; ++ky; }
    }

    // fused LSTM epilogue: cf = gate (i,f,g,o), channel = wv*16+lm
    const int ch = (wv << 4) + lm;
    #pragma unroll
    for (int f = 0; f < 4; ++f){
        int pxb = (pb << 6) + (f << 4) + (lg << 2);
        f32x4v g4[4];
        #pragma unroll
        for (int cf = 0; cf < 4; ++cf){
            if (initp){
                int slot = wbase + (cf << 4) + lm;
                g4[cf] = *(const f32x4v*)(initp + (((size_t)n * 256 + slot) << 10) + pxb);
            } else {
                float b = bias[(cf << 6) + ch];
                f32x4v bb = {b, b, b, b};
                g4[cf] = bb;
            }
        }
        #pragma unroll
        for (int reg = 0; reg < 4; ++reg){
            float ig = acc[f][0][reg] + g4[0][reg];
            float fg = acc[f][1][reg] + g4[1][reg];
            float gg = acc[f][2][reg] + g4[2][reg];
            float og = acc[f][3][reg] + g4[3][reg];
            int px = pxb + reg;
            size_t o = ((((size_t)n << 10) + px) << 6) + ch;
            float cv = cst[o];
            float c2 = sigmoidf(fg) * cv + sigmoidf(ig) * tanhf(gg);
            cst[o] = c2;
            hout[o] = f2bf(sigmoidf(og) * tanhf(c2));
        }
    }
}

// ---------------- gauss head: 1x1 conv 128->64 on NHWC f32 h2; z -> zs_n[0] bf16, KL
__global__ __launch_bounds__(256) void gauss_k(const float* __restrict__ h,
                                               const float* __restrict__ Wg,
                                               const float* __restrict__ bg,
                                               const float* __restrict__ eps0,
                                               ushort_t* __restrict__ zn,
                                               float* __restrict__ kl_out){
    __shared__ float w[64 * 128];
    int flat = blockIdx.x * 256 + threadIdx.x;     // [n][zc][pix]
    int pix = flat & 1023, zc = (flat >> 10) & 31, n = flat >> 15;
    for (int i = threadIdx.x; i < 64 * 128; i += 256) w[i] = Wg[i];
    __syncthreads();
    const float* hb = h + ((((size_t)n << 10) + pix) << 7);
    float amu = bg[zc], alv = bg[zc + 32];
    for (int ci = 0; ci < HDIM; ++ci){
        float hv = hb[ci];
        amu += hv * w[zc * 128 + ci];
        alv += hv * w[(zc + 32) * 128 + ci];
    }
    float s = softplusf(alv + 0.5f) + 1e-8f;
    float z = amu + s * eps0[flat];
    zn[((((size_t)n << 10) + pix) << 5) + zc] = f2bf(z);
    float kl = -logf(s) + 0.5f * (s * s + amu * amu) - 0.5f;
    kl_out[(size_t)flat * KSTEPS + 0] = kl;
}

// ---------------- fused postlin + priorlin + KL + z-sample
__global__ __launch_bounds__(256) void postprior_k(const ushort_t* __restrict__ hq,
                                                   const ushort_t* __restrict__ hp,
                                                   const float* __restrict__ Wq,
                                                   const float* __restrict__ bq,
                                                   const float* __restrict__ Wp,
                                                   const float* __restrict__ bp,
                                                   const float* __restrict__ eps_s,
                                                   ushort_t* __restrict__ zn_next,
                                                   float* __restrict__ kl_out, int step){
    __shared__ float wq[64 * 64];
    __shared__ float wp[64 * 64];
    int flat = blockIdx.x * 256 + threadIdx.x;     // [n][zc][pix]
    int pix = flat & 1023, zc = (flat >> 10) & 31, n = flat >> 15;
    for (int i = threadIdx.x; i < 4096; i += 256){ wq[i] = Wq[i]; wp[i] = Wp[i]; }
    __syncthreads();
    const ushort_t* hqb = hq + ((((size_t)n << 10) + pix) << 6);
    const ushort_t* hpb = hp + ((((size_t)n << 10) + pix) << 6);
    float qmu = bq[zc], qlv = bq[zc + 32], pmu = bp[zc], plv = bp[zc + 32];
    #pragma unroll
    for (int j = 0; j < 8; ++j){
        bf16x8 vq = *(const bf16x8*)(hqb + (j << 3));
        bf16x8 vp = *(const bf16x8*)(hpb + (j << 3));
        #pragma unroll
        for (int e = 0; e < 8; ++e){
            int ci = (j << 3) + e;
            float hv = bf2f((ushort_t)vq[e]);
            float pv = bf2f((ushort_t)vp[e]);
            qmu = fmaf(hv, wq[zc * 64 + ci], qmu);
            qlv = fmaf(hv, wq[(zc + 32) * 64 + ci], qlv);
            pmu = fmaf(pv, wp[zc * 64 + ci], pmu);
            plv = fmaf(pv, wp[(zc + 32) * 64 + ci], plv);
        }
    }
    float qsv = softplusf(qlv + 0.5f) + 1e-8f;
    float psv = softplusf(plv + 0.5f) + 1e-8f;
    float z = qmu + qsv * eps_s[flat];
    zn_next[((((size_t)n << 10) + pix) << 5) + zc] = f2bf(z);
    float d = qmu - pmu;
    float kl = logf(psv / qsv) + (qsv * qsv + d * d) / (2.f * psv * psv) - 0.5f;
    kl_out[(size_t)flat * KSTEPS + step] = kl;
}

// ---------------- dec1 MFMA: conv_transpose 4x4 s2 SAME, 32->128, 32x32 -> 64x64, ReLU
// parity-decomposed: grid (16 pb, 2 py, 32 n); 4 waves = 2 x-parities x 2 co-halves
#define D1CP 40
__global__ __launch_bounds__(256) void dec1m_k(const ushort_t* __restrict__ zn, // [n][1024][32]
                                               const ushort_t* __restrict__ wb, // [16][128][32]
                                               const float* __restrict__ bias,
                                               ushort_t* __restrict__ out){     // [n][4096][128]
    __shared__ ushort_t sm[105 * D1CP];
    const int pb = blockIdx.x, py = blockIdx.y, n = blockIdx.z;
    const int tid = threadIdx.x, lane = tid & 63, wv = tid >> 6;
    const int pq = wv >> 1, ch = wv & 1;
    const int lm = lane & 15, lg = lane >> 4;

    // stage rows iy = 2pb+py-1 .. 2pb+py+1 (3), cols ix -1..33 (35), 32 ci
    for (int idx = tid; idx < 105 * 4; idx += 256){
        int ci8 = idx & 3, cell = idx >> 2;
        int r = cell / 35, c = cell - r * 35;
        int iy = 2 * pb + py - 1 + r, ix = c - 1;
        bf16x8 v = {0,0,0,0,0,0,0,0};
        if ((unsigned)iy < 32u && (unsigned)ix < 32u)
            v = *(const bf16x8*)(zn + (((size_t)((n << 10) + (iy << 5) + ix)) << 5) + (ci8 << 3));
        *(bf16x8*)(sm + cell * D1CP + (ci8 << 3)) = v;
    }
    __syncthreads();

    f32x4v z4 = {0.f, 0.f, 0.f, 0.f};
    f32x4v acc[4][4];
    #pragma unroll
    for (int f = 0; f < 4; ++f)
        #pragma unroll
        for (int cf = 0; cf < 4; ++cf) acc[f][cf] = z4;

    #pragma unroll
    for (int m = 0; m < 2; ++m){
        #pragma unroll
        for (int l = 0; l < 2; ++l){
            int tap = ((py + 2 * m) << 2) + pq + 2 * l;
            bf16x8 a[4];
            #pragma unroll
            for (int f = 0; f < 4; ++f){
                int cell = ((f >> 1) + m) * 35 + ((f & 1) << 4) + lm + pq + l;
                a[f] = *(const bf16x8*)(sm + cell * D1CP + (lg << 3));
            }
            const ushort_t* wp = wb + ((size_t)((tap << 7) + (ch << 6) + lm) << 5) + (lg << 3);
            #pragma unroll
            for (int cf = 0; cf < 4; ++cf){
                bf16x8 b = *(const bf16x8*)(wp + (cf << 9));
                #pragma unroll
                for (int f = 0; f < 4; ++f)
                    acc[f][cf] = __builtin_amdgcn_mfma_f32_16x16x32_bf16(a[f], b, acc[f][cf], 0, 0, 0);
            }
        }
    }

    #pragma unroll
    for (int f = 0; f < 4; ++f){
        #pragma unroll
        for (int cf = 0; cf < 4; ++cf){
            int co = (ch << 6) + (cf << 4) + lm;
            float b = bias[co];
            #pragma unroll
            for (int reg = 0; reg < 4; ++reg){
                int qpix = (pb << 6) + (f << 4) + (lg << 2) + reg;
                int qy = qpix >> 5, qx = qpix & 31;
                int oy = 2 * qy + py, ox = 2 * qx + pq;
                float v = fmaxf(acc[f][cf][reg] + b, 0.f);
                out[(((size_t)(n << 12) + (oy << 6) + ox) << 7) + co] = f2bf(v);
            }
        }
    }
}

// ---------------- dec2: conv_transpose 4x4 s2 SAME, 128->1, NHWC bf16 in, 64x64 -> 128x128
__global__ __launch_bounds__(256) void dec2n_k(const ushort_t* __restrict__ a,  // [n][4096][128]
                                               const float* __restrict__ wT,    // [16][128]
                                               const float* __restrict__ bias,
                                               float* __restrict__ out){        // [n][16384]
    __shared__ float w[2048];
    int flat = blockIdx.x * 256 + threadIdx.x;     // [n][oy][ox]
    int ox = flat & 127, oy = (flat >> 7) & 127, n = flat >> 14;
    for (int i = threadIdx.x; i < 2048; i += 256) w[i] = wT[i];
    __syncthreads();
    float acc = bias[0];
    #pragma unroll
    for (int ky = 0; ky < 4; ++ky){
        int t = oy - 2 + ky;
        if (t & 1) continue;
        int iy = t >> 1;
        if ((unsigned)iy >= 64u) continue;
        #pragma unroll
        for (int kx = 0; kx < 4; ++kx){
            int tx = ox - 2 + kx;
            if (tx & 1) continue;
            int ix = tx >> 1;
            if ((unsigned)ix >= 64u) continue;
            const ushort_t* ap = a + (((size_t)(n << 12) + (iy << 6) + ix) << 7);
            const float* wp = w + ((ky * 4 + kx) << 7);
            #pragma unroll
            for (int j = 0; j < 16; ++j){
                bf16x8 v = *(const bf16x8*)(ap + (j << 3));
                #pragma unroll
                for (int e = 0; e < 8; ++e)
                    acc = fmaf(bf2f((ushort_t)v[e]), wp[(j << 3) + e], acc);
            }
        }
    }
    out[flat] = acc;
}

// ---------------- stick-breaking over K decoder outputs
__global__ __launch_bounds__(256) void stick_k(const float* __restrict__ dec,
                                               float* __restrict__ lm){
    int flat = blockIdx.x * 256 + threadIdx.x;
    float ss = 0.f;
    #pragma unroll
    for (int k = 0; k < KSTEPS; ++k){
        float v = dec[(size_t)k * (BATCH * 16384) + flat];
        if (k < KSTEPS - 1){
            lm[(size_t)k * (BATCH * 16384) + flat] = ss + logsigf(v);
            ss += logsigf(-v);
        } else {
            lm[(size_t)k * (BATCH * 16384) + flat] = ss + logsigf(v);
        }
    }
}

extern "C" void kernel_launch(void* const* d_in, const int* in_sizes, int n_in,
                              void* d_out, int out_size, void* d_ws, size_t ws_size,
                              hipStream_t stream){
    const float* x        = (const float*)d_in[0];
    const float* eps      = (const float*)d_in[1];
    const float* stem1_W  = (const float*)d_in[2];
    const float* stem1_b  = (const float*)d_in[3];
    const float* stem2_W  = (const float*)d_in[4];
    const float* stem2_b  = (const float*)d_in[5];
    const float* gauss_W  = (const float*)d_in[6];
    const float* gauss_b  = (const float*)d_in[7];
    const float* post_Wx  = (const float*)d_in[8];
    const float* post_Wh  = (const float*)d_in[9];
    const float* post_b   = (const float*)d_in[10];
    const float* postlin_W= (const float*)d_in[11];
    const float* postlin_b= (const float*)d_in[12];
    const float* prior_Wx = (const float*)d_in[13];
    const float* prior_Wh = (const float*)d_in[14];
    const float* prior_b  = (const float*)d_in[15];
    const float* priorlin_W=(const float*)d_in[16];
    const float* priorlin_b=(const float*)d_in[17];
    const float* dec1_W   = (const float*)d_in[18];
    const float* dec1_b   = (const float*)d_in[19];
    const float* dec2_W   = (const float*)d_in[20];
    const float* dec2_b   = (const float*)d_in[21];

    float* lm_out = (float*)d_out;
    float* kl_out = lm_out + (size_t)KSTEPS * BATCH * 16384;

    float* p = (float*)d_ws;
    ushort_t* h1n = (ushort_t*)p; p += (size_t)16777216;             // 33.5 MB bf16 [32][4096][128]; d1out alias
    float* pregates = p; p += (size_t)BATCH * 256 * 1024;            // 33.5 MB f32 slot layout
    float* h2f   = p; p += (size_t)BATCH * HDIM * 1024;              // 16.8 MB f32 NHWC (dco alias)
    float* cq    = p; p += (size_t)BATCH * 64 * 1024;                // zeroed
    float* cp    = p; p += (size_t)BATCH * 64 * 1024;                // zeroed
    ushort_t* hq_a = (ushort_t*)p; p += (size_t)BATCH * 64 * 1024 / 2;  // zeroed
    ushort_t* hp_a = (ushort_t*)p; p += (size_t)BATCH * 64 * 1024 / 2;  // zeroed
    ushort_t* hq_b = (ushort_t*)p; p += (size_t)BATCH * 64 * 1024 / 2;
    ushort_t* hp_b = (ushort_t*)p; p += (size_t)BATCH * 64 * 1024 / 2;
    ushort_t* zs_n = (ushort_t*)p; p += (size_t)KSTEPS * BATCH * ZDIM * 1024 / 2; // [6][32][1024][32] bf16
    ushort_t* h2_n = (ushort_t*)p; p += (size_t)BATCH * HDIM * 1024 / 2;          // [32][1024][128] bf16
    ushort_t* w_pre   = (ushort_t*)p; p += 409600;   // 25*4*256*32 = 819200 us
    ushort_t* w_post  = (ushort_t*)p; p += 307200;   // 614400 us
    ushort_t* w_prior = (ushort_t*)p; p += 307200;
    ushort_t* w_stem2 = (ushort_t*)p; p += 204800;   // 409600 us
    ushort_t* wdec1b  = (ushort_t*)p; p += 32768;    // 65536 us
    float* wstem1 = p; p += 9600;
    float* wdec2T = p; p += 2048;

    ushort_t* d1out = h1n;     // decoder phase reuse (bf16 [32][4096][128])
    float* dco = h2f;          // [6][32][16384] f32 fits in h2f slot

    // zero c_q, c_p (f32) + h_q_a, h_p_a (bf16) — contiguous
    hipMemsetAsync(cq, 0, (size_t)2097152 * 4 * 2 + (size_t)2097152 * 2 * 2, stream);

    // weight conversions
    cvtw_k<<<3200, 256, 0, stream>>>(post_Wx, w_pre, 160, 0, 4, 0, 4, 256, 1);
    cvtw_k<<<800, 256, 0, stream>>>(post_Wx, w_post, 160, 128, 1, 0, 3, 256, 1);
    cvtw_k<<<1600, 256, 0, stream>>>(post_Wh, w_post, 64, 0, 2, 1, 3, 256, 1);
    cvtw_k<<<800, 256, 0, stream>>>(prior_Wx, w_prior, 32, 0, 1, 0, 3, 256, 1);
    cvtw_k<<<1600, 256, 0, stream>>>(prior_Wh, w_prior, 64, 0, 2, 1, 3, 256, 1);
    cvtw_k<<<1600, 256, 0, stream>>>(stem2_W, w_stem2, 128, 0, 4, 0, 4, 128, 0);
    dec1wb_k<<<256, 256, 0, stream>>>(dec1_W, wdec1b);
    dec2wt_k<<<8, 256, 0, stream>>>(dec2_W, wdec2T);
    stem1wt_k<<<38, 256, 0, stream>>>(stem1_W, wstem1);

    stem1_k<<<dim3(256, 32), 256, 0, stream>>>(x, wstem1, stem1_b, h1n);
    s2m_k<<<dim3(16, 32), 256, 0, stream>>>(h1n, w_stem2, stem2_b, h2f, h2_n);
    gauss_k<<<4096, 256, 0, stream>>>(h2f, gauss_W, gauss_b, eps, zs_n, kl_out);
    pregates_k<<<dim3(16, 32), 256, 0, stream>>>(h2_n, w_pre, post_b, pregates);

    ushort_t* hq_in = hq_a; ushort_t* hq_out = hq_b;
    ushort_t* hp_in = hp_a; ushort_t* hp_out = hp_b;
    for (int s = 0; s < KSTEPS - 1; ++s){
        const ushort_t* zn_s = zs_n + (size_t)s * 1048576;
        qp_gconv_k<<<dim3(16, 32, 2), 256, 0, stream>>>(
            zn_s, hq_in, hp_in, w_post, w_prior, pregates, post_b, prior_b,
            cq, cp, hq_out, hp_out);
        postprior_k<<<4096, 256, 0, stream>>>(hq_out, hp_out,
            postlin_W, postlin_b, priorlin_W, priorlin_b,
            eps + (size_t)(s + 1) * 1048576,
            zs_n + (size_t)(s + 1) * 1048576, kl_out, s + 1);
        ushort_t* t;
        t = hq_in; hq_in = hq_out; hq_out = t;
        t = hp_in; hp_in = hp_out; hp_out = t;
    }

    for (int k = 0; k < KSTEPS; ++k){
        dec1m_k<<<dim3(16, 2, 32), 256, 0, stream>>>(zs_n + (size_t)k * 1048576, wdec1b, dec1_b, d1out);
        dec2n_k<<<2048, 256, 0, stream>>>(d1out, wdec2T, dec2_b, dco + (size_t)k * BATCH * 16384);
    }
    stick_k<<<2048, 256, 0, stream>>>(dco, lm_out);
}

// Round 7
// 2153.418 us; speedup vs baseline: 40.7014x; 1.0611x over previous
//
#include <hip/hip_runtime.h>
#include <math.h>

#define BATCH 32
#define HDIM 128
#define ZDIM 32
#define KSTEPS 6

typedef unsigned short ushort_t;
using bf16x8 = __attribute__((ext_vector_type(8))) short;
using f32x4v = __attribute__((ext_vector_type(4))) float;

__device__ __forceinline__ float softplusf(float x){
    return fmaxf(x, 0.f) + log1pf(expf(-fabsf(x)));
}
__device__ __forceinline__ float logsigf(float x){
    return fminf(x, 0.f) - log1pf(expf(-fabsf(x)));
}
__device__ __forceinline__ float fsig(float x){
    return __builtin_amdgcn_rcpf(1.f + __expf(-x));
}
__device__ __forceinline__ float ftanh(float x){
    x = fminf(fmaxf(x, -15.f), 15.f);
    float e = __expf(2.f * x);
    return (e - 1.f) * __builtin_amdgcn_rcpf(e + 1.f);
}
__device__ __forceinline__ float bf2f(ushort_t u){
    return __uint_as_float(((unsigned)u) << 16);
}
__device__ __forceinline__ ushort_t f2bf(float f){
    unsigned x = __float_as_uint(f);
    unsigned r = (x + 0x7fffu + ((x >> 16) & 1u)) >> 16;
    return (ushort_t)r;
}

// ---------------- weight prep kernels ----------------
__global__ __launch_bounds__(256) void stem1wt_k(const float* __restrict__ W,
                                                 float* __restrict__ Wo){
    int idx = blockIdx.x * 256 + threadIdx.x;   // 9600
    if (idx >= 9600) return;
    int co = idx & 127, tap = idx >> 7;
    Wo[(tap << 7) + co] = W[co * 75 + tap];
}

// OIHW f32 -> [tap][ck][coN][ci32] bf16 (opt. gate-slot permute on co)
__global__ __launch_bounds__(256) void cvtw_k(const float* __restrict__ src,
                                              ushort_t* __restrict__ dst,
                                              int Cfull, int ci_off, int ncs,
                                              int ck_off, int NCHK, int NCO, int permute){
    int idx = blockIdx.x * 256 + threadIdx.x;
    int total = 25 * ncs * NCO * 32;
    if (idx >= total) return;
    int per_tap = ncs * NCO * 32;
    int tap = idx / per_tap;
    int r = idx - tap * per_tap;
    int ckl = r / (NCO * 32);
    int r2 = r - ckl * (NCO * 32);
    int co = r2 >> 5, cl = r2 & 31;
    int s = permute ? ((((co & 63) >> 4) << 6) | ((co >> 6) << 4) | (co & 15)) : co;
    float v = src[((size_t)co * Cfull + ci_off + (ckl << 5) + cl) * 25 + tap];
    dst[(((size_t)(tap * NCHK + ck_off + ckl)) * NCO + s) * 32 + cl] = f2bf(v);
}

// dec1_W [co128][ci32][tap16] f32 -> [tap16][co128][ci32] bf16
__global__ __launch_bounds__(256) void dec1wb_k(const float* __restrict__ W,
                                                ushort_t* __restrict__ Wo){
    int idx = blockIdx.x * 256 + threadIdx.x;      // 65536
    int ci = idx & 31, co = (idx >> 5) & 127, tap = idx >> 12;
    Wo[idx] = f2bf(W[(((co << 5) + ci) << 4) + tap]);
}

// dec2_W [ci128][tap16] f32 -> [tap16][ci128] f32
__global__ __launch_bounds__(256) void dec2wt_k(const float* __restrict__ W,
                                                float* __restrict__ Wo){
    int idx = blockIdx.x * 256 + threadIdx.x;      // 2048
    if (idx >= 2048) return;
    int ci = idx & 127, tap = idx >> 7;
    Wo[idx] = W[(ci << 4) + tap];
}

// ---------------- stem1: conv 5x5 s2, 3->128, 128x128 -> 64x64, ReLU, out NHWC bf16
__global__ __launch_bounds__(256) void stem1_k(const float* __restrict__ x,
                                               const float* __restrict__ WtT, // [tap75][co128]
                                               const float* __restrict__ bias,
                                               ushort_t* __restrict__ h1n){
    __shared__ float ws[75 * 128];
    __shared__ float xs[3][5][36];
    const int n = blockIdx.y, pb = blockIdx.x;
    const int oy = pb >> 2, oxb = (pb & 3) << 4;
    const int tid = threadIdx.x;
    const int co = tid & 127, ps = tid >> 7;
    for (int i = tid; i < 9600; i += 256) ws[i] = WtT[i];
    for (int idx = tid; idx < 525; idx += 256){
        int ci = idx / 175, r = (idx - ci * 175) / 35, c = idx - ci * 175 - r * 35;
        int iy = 2 * oy - 1 + r, ix = 2 * oxb - 1 + c;
        float v = 0.f;
        if ((unsigned)iy < 128u && (unsigned)ix < 128u)
            v = x[(size_t)n * 49152 + (ci << 14) + (iy << 7) + ix];
        xs[ci][r][c] = v;
    }
    __syncthreads();
    float b = bias[co];
    float acc[8];
    #pragma unroll
    for (int t = 0; t < 8; ++t) acc[t] = b;
    #pragma unroll
    for (int ci = 0; ci < 3; ++ci){
        #pragma unroll
        for (int ky = 0; ky < 5; ++ky){
            const float* row = &xs[ci][ky][0];
            #pragma unroll
            for (int kx = 0; kx < 5; ++kx){
                float wv = ws[((ci * 25 + ky * 5 + kx) << 7) + co];
                #pragma unroll
                for (int t = 0; t < 8; ++t)
                    acc[t] = fmaf(row[4 * t + 2 * ps + kx], wv, acc[t]);
            }
        }
    }
    #pragma unroll
    for (int t = 0; t < 8; ++t){
        int pix = (oy << 6) + oxb + (t << 1) + ps;
        h1n[((((size_t)n << 12) + pix) << 7) + co] = f2bf(fmaxf(acc[t], 0.f));
    }
}

// ---------------- stem2 MFMA: conv 5x5 s2 SAME, 128->128, 64x64 -> 32x32, ReLU, out bf16
#define S2CP 40
__global__ __launch_bounds__(256) void s2m_k(const ushort_t* __restrict__ h1n,
                                             const ushort_t* __restrict__ wb, // [25][4][128][32]
                                             const float* __restrict__ bias,
                                             ushort_t* __restrict__ h2n){
    __shared__ ushort_t sm[7 * 67 * S2CP];
    const int pb = blockIdx.x, n = blockIdx.y;
    const int tid = threadIdx.x, lane = tid & 63, wv = tid >> 6;
    const int ry = wv >> 1, ch_half = wv & 1;
    const int lm = lane & 15, lg = lane >> 4;

    f32x4v z4 = {0.f, 0.f, 0.f, 0.f};
    f32x4v acc[2][4];
    #pragma unroll
    for (int j = 0; j < 2; ++j)
        #pragma unroll
        for (int cf = 0; cf < 4; ++cf) acc[j][cf] = z4;

    for (int ck = 0; ck < 4; ++ck){
        __syncthreads();
        for (int idx = tid; idx < 7 * 67 * 4; idx += 256){
            int ci8 = idx & 3, cell = idx >> 2;
            int r = cell / 67, c = cell - r * 67;
            int iy = (pb << 2) - 1 + r, ix = c - 1;
            bf16x8 v = {0,0,0,0,0,0,0,0};
            if ((unsigned)iy < 64u && (unsigned)ix < 64u)
                v = *(const bf16x8*)(h1n + ((((size_t)n << 12) + (iy << 6) + ix) << 7) + (ck << 5) + (ci8 << 3));
            *(bf16x8*)(sm + cell * S2CP + (ci8 << 3)) = v;
        }
        __syncthreads();
        int ky = 0, kx = 0;
        for (int tap = 0; tap < 25; ++tap){
            bf16x8 a[2];
            #pragma unroll
            for (int j = 0; j < 2; ++j){
                int r = 2 * ry + ky;
                int c = 2 * ((j << 4) + lm) + kx;
                a[j] = *(const bf16x8*)(sm + (r * 67 + c) * S2CP + (lg << 3));
            }
            const ushort_t* wp = wb + ((size_t)(((tap * 4 + ck) << 7) + (ch_half << 6) + lm) << 5) + (lg << 3);
            #pragma unroll
            for (int cf = 0; cf < 4; ++cf){
                bf16x8 b = *(const bf16x8*)(wp + (cf << 9));
                acc[0][cf] = __builtin_amdgcn_mfma_f32_16x16x32_bf16(a[0], b, acc[0][cf], 0, 0, 0);
                acc[1][cf] = __builtin_amdgcn_mfma_f32_16x16x32_bf16(a[1], b, acc[1][cf], 0, 0, 0);
            }
            if (++kx == 5){ kx = 0; ++ky; }
        }
    }
    const int oy = 2 * pb + ry;
    #pragma unroll
    for (int j = 0; j < 2; ++j){
        #pragma unroll
        for (int cf = 0; cf < 4; ++cf){
            int co = (ch_half << 6) + (cf << 4) + lm;
            float b = bias[co];
            #pragma unroll
            for (int reg = 0; reg < 4; ++reg){
                int ox = (j << 4) + (lg << 2) + reg;
                int pix = (oy << 5) + ox;
                float v = fmaxf(acc[j][cf][reg] + b, 0.f);
                h2n[((((size_t)n << 10) + pix) << 7) + co] = f2bf(v);
            }
        }
    }
}

// ---------------- pregates: 5x5 SAME conv of h2 (128 ci), 256 slots, bias-init; 2 LDS phases
#define GCPA 72
__global__ __launch_bounds__(256) void pregates_k(
    const ushort_t* __restrict__ in0,     // NHWC bf16 [n][1024][128]
    const ushort_t* __restrict__ wb,      // [25][4][256][32]
    const float* __restrict__ bias,
    float* __restrict__ outp)
{
    __shared__ ushort_t sm[216 * GCPA];   // 31104 B
    const int pb = blockIdx.x, n = blockIdx.y;
    const int tid = threadIdx.x, lane = tid & 63, wv = tid >> 6;
    const int wbase = wv << 6;
    const int lm = lane & 15, lg = lane >> 4;
    f32x4v z4 = {0.f, 0.f, 0.f, 0.f};
    f32x4v acc[4][4];
    #pragma unroll
    for (int f = 0; f < 4; ++f)
        #pragma unroll
        for (int cf = 0; cf < 4; ++cf) acc[f][cf] = z4;

    #pragma unroll
    for (int ph = 0; ph < 2; ++ph){
        if (ph) __syncthreads();
        for (int idx = tid; idx < 216 * 8; idx += 256){
            int cell = idx >> 3;
            int c8 = (idx & 7) << 3;
            int rr = cell / 36, cc = cell - rr * 36;
            int y = pb * 2 - 2 + rr, x = cc - 2;
            bf16x8 v = {0,0,0,0,0,0,0,0};
            if ((unsigned)y < 32u && (unsigned)x < 32u){
                int pix = (y << 5) + x;
                v = *(const bf16x8*)(in0 + (((size_t)((n << 10) + pix)) << 7) + (ph << 6) + c8);
            }
            *(bf16x8*)(sm + cell * GCPA + c8) = v;
        }
        __syncthreads();
        int ky = 0, kx = 0;
        for (int tap = 0; tap < 25; ++tap){
            #pragma unroll
            for (int ckl = 0; ckl < 2; ++ckl){
                int ck = (ph << 1) + ckl;
                bf16x8 a[4];
                #pragma unroll
                for (int f = 0; f < 4; ++f){
                    int rr = (f >> 1) + ky;
                    int cc = ((f & 1) << 4) + lm + kx;
                    a[f] = *(const bf16x8*)(sm + (rr * 36 + cc) * GCPA + (ckl << 5) + (lg << 3));
                }
                const ushort_t* wp = wb + ((size_t)((((tap * 4 + ck) << 8) + wbase + lm)) << 5) + (lg << 3);
                #pragma unroll
                for (int cf = 0; cf < 4; ++cf){
                    bf16x8 b = *(const bf16x8*)(wp + (cf << 9));
                    #pragma unroll
                    for (int f = 0; f < 4; ++f)
                        acc[f][cf] = __builtin_amdgcn_mfma_f32_16x16x32_bf16(a[f], b, acc[f][cf], 0, 0, 0);
                }
            }
            if (++kx == 5){ kx = 0; ++ky; }
        }
    }

    #pragma unroll
    for (int f = 0; f < 4; ++f){
        int px = (pb << 6) + (f << 4) + (lg << 2);
        #pragma unroll
        for (int cf = 0; cf < 4; ++cf){
            int co = wbase + (cf << 4) + lm;   // slot
            int orig = (((co >> 4) & 3) << 6) | ((co >> 6) << 4) | (co & 15);
            float b = bias[orig];
            size_t o = (((size_t)n * 256 + co) << 10) + px;
            float4 st = {acc[f][cf][0] + b, acc[f][cf][1] + b, acc[f][cf][2] + b, acc[f][cf][3] + b};
            *(float4*)(outp + o) = st;
        }
    }
}

// ---------------- merged posterior+prior gate conv + fused LSTM; 2 LDS phases
__global__ __launch_bounds__(256) void qp_gconv_k(
    const ushort_t* __restrict__ zn,
    const ushort_t* __restrict__ hq_in, const ushort_t* __restrict__ hp_in,
    const ushort_t* __restrict__ w_post, const ushort_t* __restrict__ w_prior,
    const float* __restrict__ pregates,
    const float* __restrict__ post_b, const float* __restrict__ prior_b,
    float* __restrict__ cq, float* __restrict__ cp,
    ushort_t* __restrict__ hq_out, ushort_t* __restrict__ hp_out)
{
    __shared__ ushort_t sm[216 * GCPA];   // 31104 B
    const int pb = blockIdx.x, n = blockIdx.y, pr = blockIdx.z;
    const ushort_t* in1 = pr ? hp_in : hq_in;
    const ushort_t* wb  = pr ? w_prior : w_post;
    const float* initp  = pr ? (const float*)nullptr : pregates;
    const float* bias   = pr ? prior_b : post_b;
    float* cst          = pr ? cp : cq;
    ushort_t* hout      = pr ? hp_out : hq_out;

    const int tid = threadIdx.x, lane = tid & 63, wv = tid >> 6;
    const int wbase = wv << 6;
    const int lm = lane & 15, lg = lane >> 4;
    f32x4v z4 = {0.f, 0.f, 0.f, 0.f};
    f32x4v acc[4][4];
    #pragma unroll
    for (int f = 0; f < 4; ++f)
        #pragma unroll
        for (int cf = 0; cf < 4; ++cf) acc[f][cf] = z4;

    // ---- phase A: channels 0..63 (z 0:32 + h 0:32), ck 0..1
    for (int idx = tid; idx < 216 * 8; idx += 256){
        int cell = idx >> 3;
        int c8 = (idx & 7) << 3;
        int rr = cell / 36, cc = cell - rr * 36;
        int y = pb * 2 - 2 + rr, x = cc - 2;
        bf16x8 v = {0,0,0,0,0,0,0,0};
        if ((unsigned)y < 32u && (unsigned)x < 32u){
            int pix = (y << 5) + x;
            if (c8 < 32) v = *(const bf16x8*)(zn + (((size_t)((n << 10) + pix)) << 5) + c8);
            else         v = *(const bf16x8*)(in1 + (((size_t)((n << 10) + pix)) << 6) + (c8 - 32));
        }
        *(bf16x8*)(sm + cell * GCPA + c8) = v;
    }
    __syncthreads();
    {
        int ky = 0, kx = 0;
        for (int tap = 0; tap < 25; ++tap){
            #pragma unroll
            for (int ck = 0; ck < 2; ++ck){
                bf16x8 a[4];
                #pragma unroll
                for (int f = 0; f < 4; ++f){
                    int rr = (f >> 1) + ky;
                    int cc = ((f & 1) << 4) + lm + kx;
                    a[f] = *(const bf16x8*)(sm + (rr * 36 + cc) * GCPA + (ck << 5) + (lg << 3));
                }
                const ushort_t* wp = wb + ((size_t)((((tap * 3 + ck) << 8) + wbase + lm)) << 5) + (lg << 3);
                #pragma unroll
                for (int cf = 0; cf < 4; ++cf){
                    bf16x8 b = *(const bf16x8*)(wp + (cf << 9));
                    #pragma unroll
                    for (int f = 0; f < 4; ++f)
                        acc[f][cf] = __builtin_amdgcn_mfma_f32_16x16x32_bf16(a[f], b, acc[f][cf], 0, 0, 0);
                }
            }
            if (++kx == 5){ kx = 0; ++ky; }
        }
    }
    __syncthreads();
    // ---- phase B: channels 64..95 (h 32:64), ck 2
    for (int idx = tid; idx < 216 * 4; idx += 256){
        int cell = idx >> 2;
        int c8 = (idx & 3) << 3;
        int rr = cell / 36, cc = cell - rr * 36;
        int y = pb * 2 - 2 + rr, x = cc - 2;
        bf16x8 v = {0,0,0,0,0,0,0,0};
        if ((unsigned)y < 32u && (unsigned)x < 32u){
            int pix = (y << 5) + x;
            v = *(const bf16x8*)(in1 + (((size_t)((n << 10) + pix)) << 6) + 32 + c8);
        }
        *(bf16x8*)(sm + cell * GCPA + c8) = v;
    }
    __syncthreads();
    {
        int ky = 0, kx = 0;
        for (int tap = 0; tap < 25; ++tap){
            bf16x8 a[4];
            #pragma unroll
            for (int f = 0; f < 4; ++f){
                int rr = (f >> 1) + ky;
                int cc = ((f & 1) << 4) + lm + kx;
                a[f] = *(const bf16x8*)(sm + (rr * 36 + cc) * GCPA + (lg << 3));
            }
            const ushort_t* wp = wb + ((size_t)((((tap * 3 + 2) << 8) + wbase + lm)) << 5) + (lg << 3);
            #pragma unroll
            for (int cf = 0; cf < 4; ++cf){
                bf16x8 b = *(const bf16x8*)(wp + (cf << 9));
                #pragma unroll
                for (int f = 0; f < 4; ++f)
                    acc[f][cf] = __builtin_amdgcn_mfma_f32_16x16x32_bf16(a[f], b, acc[f][cf], 0, 0, 0);
            }
            if (++kx == 5){ kx = 0; ++ky; }
        }
    }

    // fused LSTM epilogue: cf = gate (i,f,g,o), channel = wv*16+lm
    const int ch = (wv << 4) + lm;
    #pragma unroll
    for (int f = 0; f < 4; ++f){
        int pxb = (pb << 6) + (f << 4) + (lg << 2);
        f32x4v g4[4];
        #pragma unroll
        for (int cf = 0; cf < 4; ++cf){
            if (initp){
                int slot = wbase + (cf << 4) + lm;
                g4[cf] = *(const f32x4v*)(initp + (((size_t)n * 256 + slot) << 10) + pxb);
            } else {
                float b = bias[(cf << 6) + ch];
                f32x4v bb = {b, b, b, b};
                g4[cf] = bb;
            }
        }
        #pragma unroll
        for (int reg = 0; reg < 4; ++reg){
            float ig = acc[f][0][reg] + g4[0][reg];
            float fg = acc[f][1][reg] + g4[1][reg];
            float gg = acc[f][2][reg] + g4[2][reg];
            float og = acc[f][3][reg] + g4[3][reg];
            int px = pxb + reg;
            size_t o = ((((size_t)n << 10) + px) << 6) + ch;
            float cv = cst[o];
            float c2 = fsig(fg) * cv + fsig(ig) * ftanh(gg);
            cst[o] = c2;
            hout[o] = f2bf(fsig(og) * ftanh(c2));
        }
    }
}

// ---------------- gauss head: 1x1 conv 128->64 on NHWC bf16 h2; z -> zs_n[0], KL
__global__ __launch_bounds__(256) void gauss_k(const ushort_t* __restrict__ h2n,
                                               const float* __restrict__ Wg,
                                               const float* __restrict__ bg,
                                               const float* __restrict__ eps0,
                                               ushort_t* __restrict__ zn,
                                               float* __restrict__ kl_out){
    __shared__ float w[64 * 128];
    int flat = blockIdx.x * 256 + threadIdx.x;     // [n][zc][pix]
    int pix = flat & 1023, zc = (flat >> 10) & 31, n = flat >> 15;
    for (int i = threadIdx.x; i < 64 * 128; i += 256) w[i] = Wg[i];
    __syncthreads();
    const ushort_t* hb = h2n + ((((size_t)n << 10) + pix) << 7);
    float amu = bg[zc], alv = bg[zc + 32];
    #pragma unroll
    for (int j = 0; j < 16; ++j){
        bf16x8 v = *(const bf16x8*)(hb + (j << 3));
        #pragma unroll
        for (int e = 0; e < 8; ++e){
            int ci = (j << 3) + e;
            float hv = bf2f((ushort_t)v[e]);
            amu = fmaf(hv, w[zc * 128 + ci], amu);
            alv = fmaf(hv, w[(zc + 32) * 128 + ci], alv);
        }
    }
    float s = softplusf(alv + 0.5f) + 1e-8f;
    float z = amu + s * eps0[flat];
    zn[((((size_t)n << 10) + pix) << 5) + zc] = f2bf(z);
    float kl = -logf(s) + 0.5f * (s * s + amu * amu) - 0.5f;
    kl_out[(size_t)flat * KSTEPS + 0] = kl;
}

// ---------------- fused postlin + priorlin + KL + z-sample
__global__ __launch_bounds__(256) void postprior_k(const ushort_t* __restrict__ hq,
                                                   const ushort_t* __restrict__ hp,
                                                   const float* __restrict__ Wq,
                                                   const float* __restrict__ bq,
                                                   const float* __restrict__ Wp,
                                                   const float* __restrict__ bp,
                                                   const float* __restrict__ eps_s,
                                                   ushort_t* __restrict__ zn_next,
                                                   float* __restrict__ kl_out, int step){
    __shared__ float wq[64 * 64];
    __shared__ float wp[64 * 64];
    int flat = blockIdx.x * 256 + threadIdx.x;     // [n][zc][pix]
    int pix = flat & 1023, zc = (flat >> 10) & 31, n = flat >> 15;
    for (int i = threadIdx.x; i < 4096; i += 256){ wq[i] = Wq[i]; wp[i] = Wp[i]; }
    __syncthreads();
    const ushort_t* hqb = hq + ((((size_t)n << 10) + pix) << 6);
    const ushort_t* hpb = hp + ((((size_t)n << 10) + pix) << 6);
    float qmu = bq[zc], qlv = bq[zc + 32], pmu = bp[zc], plv = bp[zc + 32];
    #pragma unroll
    for (int j = 0; j < 8; ++j){
        bf16x8 vq = *(const bf16x8*)(hqb + (j << 3));
        bf16x8 vp = *(const bf16x8*)(hpb + (j << 3));
        #pragma unroll
        for (int e = 0; e < 8; ++e){
            int ci = (j << 3) + e;
            float hv = bf2f((ushort_t)vq[e]);
            float pv = bf2f((ushort_t)vp[e]);
            qmu = fmaf(hv, wq[zc * 64 + ci], qmu);
            qlv = fmaf(hv, wq[(zc + 32) * 64 + ci], qlv);
            pmu = fmaf(pv, wp[zc * 64 + ci], pmu);
            plv = fmaf(pv, wp[(zc + 32) * 64 + ci], plv);
        }
    }
    float qsv = softplusf(qlv + 0.5f) + 1e-8f;
    float psv = softplusf(plv + 0.5f) + 1e-8f;
    float z = qmu + qsv * eps_s[flat];
    zn_next[((((size_t)n << 10) + pix) << 5) + zc] = f2bf(z);
    float d = qmu - pmu;
    float kl = logf(psv / qsv) + (qsv * qsv + d * d) / (2.f * psv * psv) - 0.5f;
    kl_out[(size_t)flat * KSTEPS + step] = kl;
}

// ---------------- dec1 MFMA: conv_transpose 4x4 s2 SAME, 32->128, 32x32 -> 64x64, ReLU
#define D1CP 40
__global__ __launch_bounds__(256) void dec1m_k(const ushort_t* __restrict__ zn, // [n][1024][32]
                                               const ushort_t* __restrict__ wb, // [16][128][32]
                                               const float* __restrict__ bias,
                                               ushort_t* __restrict__ out){     // [n][4096][128]
    __shared__ ushort_t sm[105 * D1CP];
    const int pb = blockIdx.x, py = blockIdx.y, n = blockIdx.z;
    const int tid = threadIdx.x, lane = tid & 63, wv = tid >> 6;
    const int pq = wv >> 1, ch = wv & 1;
    const int lm = lane & 15, lg = lane >> 4;

    for (int idx = tid; idx < 105 * 4; idx += 256){
        int ci8 = idx & 3, cell = idx >> 2;
        int r = cell / 35, c = cell - r * 35;
        int iy = 2 * pb + py - 1 + r, ix = c - 1;
        bf16x8 v = {0,0,0,0,0,0,0,0};
        if ((unsigned)iy < 32u && (unsigned)ix < 32u)
            v = *(const bf16x8*)(zn + (((size_t)((n << 10) + (iy << 5) + ix)) << 5) + (ci8 << 3));
        *(bf16x8*)(sm + cell * D1CP + (ci8 << 3)) = v;
    }
    __syncthreads();

    f32x4v z4 = {0.f, 0.f, 0.f, 0.f};
    f32x4v acc[4][4];
    #pragma unroll
    for (int f = 0; f < 4; ++f)
        #pragma unroll
        for (int cf = 0; cf < 4; ++cf) acc[f][cf] = z4;

    #pragma unroll
    for (int m = 0; m < 2; ++m){
        #pragma unroll
        for (int l = 0; l < 2; ++l){
            int tap = ((py + 2 * m) << 2) + pq + 2 * l;
            bf16x8 a[4];
            #pragma unroll
            for (int f = 0; f < 4; ++f){
                int cell = ((f >> 1) + m) * 35 + ((f & 1) << 4) + lm + pq + l;
                a[f] = *(const bf16x8*)(sm + cell * D1CP + (lg << 3));
            }
            const ushort_t* wp = wb + ((size_t)((tap << 7) + (ch << 6) + lm) << 5) + (lg << 3);
            #pragma unroll
            for (int cf = 0; cf < 4; ++cf){
                bf16x8 b = *(const bf16x8*)(wp + (cf << 9));
                #pragma unroll
                for (int f = 0; f < 4; ++f)
                    acc[f][cf] = __builtin_amdgcn_mfma_f32_16x16x32_bf16(a[f], b, acc[f][cf], 0, 0, 0);
            }
        }
    }

    #pragma unroll
    for (int f = 0; f < 4; ++f){
        #pragma unroll
        for (int cf = 0; cf < 4; ++cf){
            int co = (ch << 6) + (cf << 4) + lm;
            float b = bias[co];
            #pragma unroll
            for (int reg = 0; reg < 4; ++reg){
                int qpix = (pb << 6) + (f << 4) + (lg << 2) + reg;
                int qy = qpix >> 5, qx = qpix & 31;
                int oy = 2 * qy + py, ox = 2 * qx + pq;
                float v = fmaxf(acc[f][cf][reg] + b, 0.f);
                out[(((size_t)(n << 12) + (oy << 6) + ox) << 7) + co] = f2bf(v);
            }
        }
    }
}

// ---------------- dec2 tiled: conv_transpose 4x4 s2 SAME, 128->1, 64x64 -> 128x128
// grid (8 y-tiles, 32 n); block: 16 oy x 128 ox; input staged in LDS 32-ci chunks
__global__ __launch_bounds__(256) void dec2t_k(const ushort_t* __restrict__ a,  // [n][4096][128]
                                               const float* __restrict__ wT,    // [16][128]
                                               const float* __restrict__ bias,
                                               float* __restrict__ out){        // [n][16384]
    __shared__ ushort_t sm[660 * 40];    // 10 rows x 66 cols x (32ci + 8 pad)
    __shared__ float ws[2048];
    const int t = blockIdx.x, n = blockIdx.y;
    const int tid = threadIdx.x;
    const int oyl = tid & 15, oxb = (tid >> 4) << 3;
    const int oy = (t << 4) + oyl;
    const int py = oy & 1;
    const int iyA = (oy - 2 + py) >> 1;
    const int rA = iyA - (t << 3) + 1;
    for (int i = tid; i < 2048; i += 256) ws[i] = wT[i];

    float acc[8];
    float b0 = bias[0];
    #pragma unroll
    for (int p = 0; p < 8; ++p) acc[p] = b0;

    for (int cc = 0; cc < 4; ++cc){
        __syncthreads();
        for (int idx = tid; idx < 2640; idx += 256){
            int q = idx & 3, cell = idx >> 2;
            int r = cell / 66, c = cell - r * 66;
            int iy = (t << 3) - 1 + r, ix = c - 1;
            bf16x8 v = {0,0,0,0,0,0,0,0};
            if ((unsigned)iy < 64u && (unsigned)ix < 64u)
                v = *(const bf16x8*)(a + ((((size_t)n << 12) + (iy << 6) + ix) << 7) + (cc << 5) + (q << 3));
            *(bf16x8*)(sm + cell * 40 + (q << 3)) = v;
        }
        __syncthreads();
        #pragma unroll
        for (int p = 0; p < 8; ++p){
            int ox = oxb + p;
            int qx = ox & 1;
            int cA = ((ox - 2 + qx) >> 1) + 1;
            #pragma unroll
            for (int m = 0; m < 2; ++m){
                #pragma unroll
                for (int l = 0; l < 2; ++l){
                    const ushort_t* sp = sm + ((rA + m) * 66 + cA + l) * 40;
                    const float* wp = ws + ((((py + 2 * m) << 2) + qx + 2 * l) << 7) + (cc << 5);
                    #pragma unroll
                    for (int j = 0; j < 4; ++j){
                        bf16x8 v = *(const bf16x8*)(sp + (j << 3));
                        #pragma unroll
                        for (int e = 0; e < 8; ++e)
                            acc[p] = fmaf(bf2f((ushort_t)v[e]), wp[(j << 3) + e], acc[p]);
                    }
                }
            }
        }
    }
    size_t o = ((size_t)n << 14) + ((size_t)oy << 7) + oxb;
    float4 o0 = {acc[0], acc[1], acc[2], acc[3]};
    float4 o1 = {acc[4], acc[5], acc[6], acc[7]};
    *reinterpret_cast<float4*>(out + o) = o0;
    *reinterpret_cast<float4*>(out + o + 4) = o1;
}

// ---------------- stick-breaking over K decoder outputs
__global__ __launch_bounds__(256) void stick_k(const float* __restrict__ dec,
                                               float* __restrict__ lm){
    int flat = blockIdx.x * 256 + threadIdx.x;
    float ss = 0.f;
    #pragma unroll
    for (int k = 0; k < KSTEPS; ++k){
        float v = dec[(size_t)k * (BATCH * 16384) + flat];
        if (k < KSTEPS - 1){
            lm[(size_t)k * (BATCH * 16384) + flat] = ss + logsigf(v);
            ss += logsigf(-v);
        } else {
            lm[(size_t)k * (BATCH * 16384) + flat] = ss + logsigf(v);
        }
    }
}

extern "C" void kernel_launch(void* const* d_in, const int* in_sizes, int n_in,
                              void* d_out, int out_size, void* d_ws, size_t ws_size,
                              hipStream_t stream){
    const float* x        = (const float*)d_in[0];
    const float* eps      = (const float*)d_in[1];
    const float* stem1_W  = (const float*)d_in[2];
    const float* stem1_b  = (const float*)d_in[3];
    const float* stem2_W  = (const float*)d_in[4];
    const float* stem2_b  = (const float*)d_in[5];
    const float* gauss_W  = (const float*)d_in[6];
    const float* gauss_b  = (const float*)d_in[7];
    const float* post_Wx  = (const float*)d_in[8];
    const float* post_Wh  = (const float*)d_in[9];
    const float* post_b   = (const float*)d_in[10];
    const float* postlin_W= (const float*)d_in[11];
    const float* postlin_b= (const float*)d_in[12];
    const float* prior_Wx = (const float*)d_in[13];
    const float* prior_Wh = (const float*)d_in[14];
    const float* prior_b  = (const float*)d_in[15];
    const float* priorlin_W=(const float*)d_in[16];
    const float* priorlin_b=(const float*)d_in[17];
    const float* dec1_W   = (const float*)d_in[18];
    const float* dec1_b   = (const float*)d_in[19];
    const float* dec2_W   = (const float*)d_in[20];
    const float* dec2_b   = (const float*)d_in[21];

    float* lm_out = (float*)d_out;
    float* kl_out = lm_out + (size_t)KSTEPS * BATCH * 16384;

    float* p = (float*)d_ws;
    ushort_t* h1n = (ushort_t*)p; p += (size_t)16777216;             // 33.5 MB bf16 [32][4096][128]; d1out alias
    float* pregates = p; p += (size_t)BATCH * 256 * 1024;            // 33.5 MB f32 slot layout
    float* dco   = p; p += (size_t)KSTEPS * BATCH * 16384;           // 12.6 MB f32
    float* cq    = p; p += (size_t)BATCH * 64 * 1024;                // zeroed
    float* cp    = p; p += (size_t)BATCH * 64 * 1024;                // zeroed
    ushort_t* hq_a = (ushort_t*)p; p += (size_t)BATCH * 64 * 1024 / 2;  // zeroed
    ushort_t* hp_a = (ushort_t*)p; p += (size_t)BATCH * 64 * 1024 / 2;  // zeroed
    ushort_t* hq_b = (ushort_t*)p; p += (size_t)BATCH * 64 * 1024 / 2;
    ushort_t* hp_b = (ushort_t*)p; p += (size_t)BATCH * 64 * 1024 / 2;
    ushort_t* zs_n = (ushort_t*)p; p += (size_t)KSTEPS * BATCH * ZDIM * 1024 / 2; // [6][32][1024][32] bf16
    ushort_t* h2_n = (ushort_t*)p; p += (size_t)BATCH * HDIM * 1024 / 2;          // [32][1024][128] bf16
    ushort_t* w_pre   = (ushort_t*)p; p += 409600;   // 25*4*256*32 = 819200 us
    ushort_t* w_post  = (ushort_t*)p; p += 307200;   // 614400 us
    ushort_t* w_prior = (ushort_t*)p; p += 307200;
    ushort_t* w_stem2 = (ushort_t*)p; p += 204800;   // 409600 us
    ushort_t* wdec1b  = (ushort_t*)p; p += 32768;    // 65536 us
    float* wstem1 = p; p += 9600;
    float* wdec2T = p; p += 2048;

    ushort_t* d1out = h1n;     // decoder phase reuse (bf16 [32][4096][128])

    // zero c_q, c_p (f32) + h_q_a, h_p_a (bf16) — contiguous
    hipMemsetAsync(cq, 0, (size_t)2097152 * 4 * 2 + (size_t)2097152 * 2 * 2, stream);

    // weight conversions
    cvtw_k<<<3200, 256, 0, stream>>>(post_Wx, w_pre, 160, 0, 4, 0, 4, 256, 1);
    cvtw_k<<<800, 256, 0, stream>>>(post_Wx, w_post, 160, 128, 1, 0, 3, 256, 1);
    cvtw_k<<<1600, 256, 0, stream>>>(post_Wh, w_post, 64, 0, 2, 1, 3, 256, 1);
    cvtw_k<<<800, 256, 0, stream>>>(prior_Wx, w_prior, 32, 0, 1, 0, 3, 256, 1);
    cvtw_k<<<1600, 256, 0, stream>>>(prior_Wh, w_prior, 64, 0, 2, 1, 3, 256, 1);
    cvtw_k<<<1600, 256, 0, stream>>>(stem2_W, w_stem2, 128, 0, 4, 0, 4, 128, 0);
    dec1wb_k<<<256, 256, 0, stream>>>(dec1_W, wdec1b);
    dec2wt_k<<<8, 256, 0, stream>>>(dec2_W, wdec2T);
    stem1wt_k<<<38, 256, 0, stream>>>(stem1_W, wstem1);

    stem1_k<<<dim3(256, 32), 256, 0, stream>>>(x, wstem1, stem1_b, h1n);
    s2m_k<<<dim3(16, 32), 256, 0, stream>>>(h1n, w_stem2, stem2_b, h2_n);
    gauss_k<<<4096, 256, 0, stream>>>(h2_n, gauss_W, gauss_b, eps, zs_n, kl_out);
    pregates_k<<<dim3(16, 32), 256, 0, stream>>>(h2_n, w_pre, post_b, pregates);

    ushort_t* hq_in = hq_a; ushort_t* hq_out = hq_b;
    ushort_t* hp_in = hp_a; ushort_t* hp_out = hp_b;
    for (int s = 0; s < KSTEPS - 1; ++s){
        const ushort_t* zn_s = zs_n + (size_t)s * 1048576;
        qp_gconv_k<<<dim3(16, 32, 2), 256, 0, stream>>>(
            zn_s, hq_in, hp_in, w_post, w_prior, pregates, post_b, prior_b,
            cq, cp, hq_out, hp_out);
        postprior_k<<<4096, 256, 0, stream>>>(hq_out, hp_out,
            postlin_W, postlin_b, priorlin_W, priorlin_b,
            eps + (size_t)(s + 1) * 1048576,
            zs_n + (size_t)(s + 1) * 1048576, kl_out, s + 1);
        ushort_t* t;
        t = hq_in; hq_in = hq_out; hq_out = t;
        t = hp_in; hp_in = hp_out; hp_out = t;
    }

    for (int k = 0; k < KSTEPS; ++k){
        dec1m_k<<<dim3(16, 2, 32), 256, 0, stream>>>(zs_n + (size_t)k * 1048576, wdec1b, dec1_b, d1out);
        dec2t_k<<<dim3(8, 32), 256, 0, stream>>>(d1out, wdec2T, dec2_b, dco + (size_t)k * BATCH * 16384);
    }
    stick_k<<<2048, 256, 0, stream>>>(dco, lm_out);
}